// Round 5
// baseline (127.347 us; speedup 1.0000x reference)
//
#include <hip/hip_runtime.h>
#include <hip/hip_bf16.h>
#include <stdint.h>

typedef float f32x4 __attribute__((ext_vector_type(4)));
typedef __bf16 bf16x8 __attribute__((ext_vector_type(8)));

#define T_SEQ 2048
#define D_EMB 1024
#define H_DIM 128
#define NBATCH 8
#define NTOK 16384  // NBATCH * T_SEQ

typedef __attribute__((address_space(3))) uint32_t lds_u32;
typedef const __attribute__((address_space(1))) uint32_t glb_u32;

// ---------------------------------------------------------------------------
// ws layout (bf16 elements):
//   Wt : [3][128][1024]   transposed weights (W^T), q|k|v
//   qb : [16384][128]     Q bf16
//   kb : [16384][128]     K bf16
//   vt : [8][128][2048]   V transposed per batch (PV B-frags contiguous)
// ---------------------------------------------------------------------------

__global__ __launch_bounds__(256) void prep_w_kernel(
    const float* __restrict__ Wq, const float* __restrict__ Wk,
    const float* __restrict__ Wv, __hip_bfloat16* __restrict__ Wt) {
  const int mat = blockIdx.x >> 7;   // 0..2
  const int h = blockIdx.x & 127;
  const float* W = (mat == 0) ? Wq : ((mat == 1) ? Wk : Wv);
  __hip_bfloat16* dst = Wt + (size_t)(mat * 128 + h) * D_EMB;
  for (int k = threadIdx.x; k < D_EMB; k += 256)
    dst[k] = __float2bfloat16(W[(size_t)k * H_DIM + h]);
}

// Projection GEMM, m97-style: C[16384,384] = xb * Wt^T.
// BM=64 x BN=384 (full N -> x read exactly once) x BK=64.
__global__ __launch_bounds__(512) void proj_kernel(
    const float* __restrict__ x, const __hip_bfloat16* __restrict__ Wt,
    __hip_bfloat16* __restrict__ qb, __hip_bfloat16* __restrict__ kb,
    __hip_bfloat16* __restrict__ vt) {
  __shared__ __align__(16) __hip_bfloat16 As[64 * 64];    // 8 KB
  __shared__ __align__(16) __hip_bfloat16 Bs[384 * 64];   // 48 KB
  const int tid = threadIdx.x;
  const int wave = tid >> 6;
  const int lane = tid & 63;
  const int g = lane >> 4;
  const int lr = lane & 15;
  const int m0 = blockIdx.x * 64;
  const int wc = wave * 48;

  f32x4 acc[4][3];
#pragma unroll
  for (int m = 0; m < 4; ++m)
#pragma unroll
    for (int n = 0; n < 3; ++n) acc[m][n] = f32x4{0.f, 0.f, 0.f, 0.f};

  const int arow = tid >> 3;        // 0..63
  const int acol = (tid & 7) * 8;   // 0..56
  const float* asrc = x + (size_t)(m0 + arow) * D_EMB + acol;
  __hip_bfloat16* adst = &As[arow * 64 + (acol ^ ((arow & 7) * 8))];

  for (int k0 = 0; k0 < D_EMB; k0 += 64) {
    __syncthreads();
#pragma unroll
    for (int i = 0; i < 6; ++i) {
      const int e = (i * 512 + tid) * 8;   // bf16 element index
      const int br = e >> 6;
      const int bc = e & 63;
      __builtin_amdgcn_global_load_lds(
          (glb_u32*)(uintptr_t)(Wt + (size_t)br * D_EMB + k0 + bc),
          (lds_u32*)(uintptr_t)(&Bs[e]), 16, 0, 0);
    }
    {
      const float4 f0 = *reinterpret_cast<const float4*>(asrc + k0);
      const float4 f1 = *reinterpret_cast<const float4*>(asrc + k0 + 4);
      union { bf16x8 v; __hip_bfloat16 h[8]; } u;
      u.h[0] = __float2bfloat16(f0.x);
      u.h[1] = __float2bfloat16(f0.y);
      u.h[2] = __float2bfloat16(f0.z);
      u.h[3] = __float2bfloat16(f0.w);
      u.h[4] = __float2bfloat16(f1.x);
      u.h[5] = __float2bfloat16(f1.y);
      u.h[6] = __float2bfloat16(f1.z);
      u.h[7] = __float2bfloat16(f1.w);
      *reinterpret_cast<bf16x8*>(adst) = u.v;
    }
    __syncthreads();
#pragma unroll
    for (int kk = 0; kk < 2; ++kk) {
      bf16x8 a[4];
#pragma unroll
      for (int m = 0; m < 4; ++m) {
        const int row = m * 16 + lr;
        a[m] = *reinterpret_cast<const bf16x8*>(
            &As[row * 64 + ((kk * 32 + g * 8) ^ ((row & 7) * 8))]);
      }
#pragma unroll
      for (int n = 0; n < 3; ++n) {
        bf16x8 b = *reinterpret_cast<const bf16x8*>(
            &Bs[(size_t)(wc + n * 16 + lr) * 64 + kk * 32 + g * 8]);
#pragma unroll
        for (int m = 0; m < 4; ++m)
          acc[m][n] =
              __builtin_amdgcn_mfma_f32_16x16x32_bf16(a[m], b, acc[m][n], 0, 0, 0);
      }
    }
  }

#pragma unroll
  for (int n = 0; n < 3; ++n) {
    const int ng = wc + n * 16 + lr;  // 0..383
    const int head = ng >> 7;         // 0:q 1:k 2:v
    const int h = ng & 127;
#pragma unroll
    for (int m = 0; m < 4; ++m) {
#pragma unroll
      for (int r = 0; r < 4; ++r) {
        const int row = m0 + m * 16 + g * 4 + r;  // global token
        const __hip_bfloat16 val = __float2bfloat16(acc[m][n][r]);
        if (head == 0) {
          qb[(size_t)row * H_DIM + h] = val;
        } else if (head == 1) {
          kb[(size_t)row * H_DIM + h] = val;
        } else {
          const int bi = row >> 11;
          const int t = row & (T_SEQ - 1);
          vt[((size_t)bi * H_DIM + h) * T_SEQ + t] = val;
        }
      }
    }
  }
}

// Flash attention, key-parallel (8-way) + software-pipelined:
// grid = B * T/16 blocks; block = 8 waves, same 16 q rows; wave w handles
// key-blocks kbi ≡ w (mod 8) with private (m,l,O); 3-round LDS tree merge.
// Pipeline: QK^T consumes kf then kf reloads for next iter (stride 8);
// V loads issue before softmax so their latency hides under exp/shuffles.
__global__ __launch_bounds__(512, 3) void attn_kernel(
    const __hip_bfloat16* __restrict__ qb, const __hip_bfloat16* __restrict__ kb,
    const __hip_bfloat16* __restrict__ vt, float* __restrict__ out) {
  __shared__ __align__(16) char shraw[4 * 16 * 132 * 4];  // 33.8 KB overlay
  auto Pl = reinterpret_cast<__hip_bfloat16(*)[16][40]>(shraw);  // [8][16][40]
  auto Obuf = reinterpret_cast<float(*)[16][132]>(shraw);        // [4][16][132]
  __shared__ float mbuf[8][16];
  __shared__ float lbuf[8][16];
  const int tid = threadIdx.x;
  const int wave = tid >> 6;
  const int lane = tid & 63;
  const int g = lane >> 4;
  const int lr = lane & 15;
  const int idx = blockIdx.x;
  const int b = idx & 7;
  const int rg = 127 - (idx >> 3);      // heavy row-groups dispatched first
  const int qr0 = rg * 16;

  const __hip_bfloat16* qB = qb + (size_t)b * T_SEQ * H_DIM;
  const __hip_bfloat16* kB = kb + (size_t)b * T_SEQ * H_DIM;
  const __hip_bfloat16* vB = vt + (size_t)b * H_DIM * T_SEQ;

  bf16x8 qf[4];
#pragma unroll
  for (int kt = 0; kt < 4; ++kt)
    qf[kt] = *reinterpret_cast<const bf16x8*>(
        qB + (size_t)(qr0 + lr) * H_DIM + kt * 32 + g * 8);

  f32x4 oacc[8];
#pragma unroll
  for (int i = 0; i < 8; ++i) oacc[i] = f32x4{0.f, 0.f, 0.f, 0.f};
  float mrow[4] = {-1e30f, -1e30f, -1e30f, -1e30f};
  float lrow[4] = {0.f, 0.f, 0.f, 0.f};

  const float scale = 0.08838834764831845f;  // 1/sqrt(128)
  const int nkb = (qr0 + 16 + 31) >> 5;      // 32-key blocks needed

  if (wave < nkb) {
    // ---- preamble: load K fragments for first key-block ----
    bf16x8 kf[8];
    {
      const int s0 = wave * 32;
#pragma unroll
      for (int nt = 0; nt < 2; ++nt)
#pragma unroll
        for (int kt = 0; kt < 4; ++kt)
          kf[nt * 4 + kt] = *reinterpret_cast<const bf16x8*>(
              kB + (size_t)(s0 + nt * 16 + lr) * H_DIM + kt * 32 + g * 8);
    }
    for (int kbi = wave; kbi < nkb; kbi += 8) {
      const int s0 = kbi * 32;
      // ---- QK^T (consumes kf) ----
      f32x4 sacc[2];
      sacc[0] = f32x4{0.f, 0.f, 0.f, 0.f};
      sacc[1] = f32x4{0.f, 0.f, 0.f, 0.f};
#pragma unroll
      for (int nt = 0; nt < 2; ++nt)
#pragma unroll
        for (int kt = 0; kt < 4; ++kt)
          sacc[nt] = __builtin_amdgcn_mfma_f32_16x16x32_bf16(
              qf[kt], kf[nt * 4 + kt], sacc[nt], 0, 0, 0);
      // ---- prefetch K for next iteration (latency hidden by softmax+PV) ----
      {
        const int s0n = (kbi + 8 < nkb) ? (kbi + 8) * 32 : 0;
#pragma unroll
        for (int nt = 0; nt < 2; ++nt)
#pragma unroll
          for (int kt = 0; kt < 4; ++kt)
            kf[nt * 4 + kt] = *reinterpret_cast<const bf16x8*>(
                kB + (size_t)(s0n + nt * 16 + lr) * H_DIM + kt * 32 + g * 8);
      }
      // ---- V loads for current block (latency hidden by softmax) ----
      bf16x8 vf[8];
#pragma unroll
      for (int ht = 0; ht < 8; ++ht)
        vf[ht] = *reinterpret_cast<const bf16x8*>(
            vB + (size_t)(ht * 16 + lr) * T_SEQ + s0 + g * 8);
      // ---- scale + causal mask ----
      float sv[2][4];
#pragma unroll
      for (int nt = 0; nt < 2; ++nt)
#pragma unroll
        for (int r = 0; r < 4; ++r) {
          const int key = s0 + nt * 16 + lr;
          const int qr = qr0 + g * 4 + r;
          const float s = sacc[nt][r] * scale;
          sv[nt][r] = (key > qr) ? -1e30f : s;
        }
      // ---- row max over 32 keys ----
      float pm[4];
#pragma unroll
      for (int r = 0; r < 4; ++r) pm[r] = fmaxf(sv[0][r], sv[1][r]);
#pragma unroll
      for (int m = 1; m < 16; m <<= 1)
#pragma unroll
        for (int r = 0; r < 4; ++r) pm[r] = fmaxf(pm[r], __shfl_xor(pm[r], m, 64));
      // ---- defer-rescale (T13): only rescale when max grew past THR=8 ----
      bool ok = true;
#pragma unroll
      for (int r = 0; r < 4; ++r) ok = ok && (pm[r] <= mrow[r] + 8.f);
      if (!__all((int)ok)) {
#pragma unroll
        for (int r = 0; r < 4; ++r) {
          const float mnew = fmaxf(mrow[r], pm[r]);
          const float corr = __expf(mrow[r] - mnew);
          mrow[r] = mnew;
          lrow[r] *= corr;
#pragma unroll
          for (int ht = 0; ht < 8; ++ht) oacc[ht][r] *= corr;
        }
      }
      // ---- P = exp(S - m), write wave-private LDS tile, row-sum ----
      float rs[4];
#pragma unroll
      for (int r = 0; r < 4; ++r) {
        const float p0 = __expf(sv[0][r] - mrow[r]);
        const float p1 = __expf(sv[1][r] - mrow[r]);
        Pl[wave][g * 4 + r][lr] = __float2bfloat16(p0);
        Pl[wave][g * 4 + r][16 + lr] = __float2bfloat16(p1);
        rs[r] = p0 + p1;
      }
#pragma unroll
      for (int m = 1; m < 16; m <<= 1)
#pragma unroll
        for (int r = 0; r < 4; ++r) rs[r] += __shfl_xor(rs[r], m, 64);
#pragma unroll
      for (int r = 0; r < 4; ++r) lrow[r] += rs[r];
      // ---- PV ----
      bf16x8 pf = *reinterpret_cast<const bf16x8*>(&Pl[wave][lr][g * 8]);
#pragma unroll
      for (int ht = 0; ht < 8; ++ht)
        oacc[ht] = __builtin_amdgcn_mfma_f32_16x16x32_bf16(pf, vf[ht], oacc[ht], 0, 0, 0);
    }
  }

  // ---- cross-wave merge (3-round tree through LDS) ----
  // NB: the first __syncthreads below also fences the Pl/Obuf LDS overlay.
  if (lr == 0) {
#pragma unroll
    for (int r = 0; r < 4; ++r) {
      mbuf[wave][g * 4 + r] = mrow[r];
      lbuf[wave][g * 4 + r] = lrow[r];
    }
  }
  __syncthreads();
#pragma unroll
  for (int half = 4; half >= 1; half >>= 1) {
    if (wave >= half && wave < 2 * half) {
#pragma unroll
      for (int ht = 0; ht < 8; ++ht)
#pragma unroll
        for (int r = 0; r < 4; ++r)
          Obuf[wave - half][g * 4 + r][ht * 16 + lr] = oacc[ht][r];
    }
    __syncthreads();
    if (wave < half) {
      float a[4], bt[4];
#pragma unroll
      for (int r = 0; r < 4; ++r) {
        const float mB = mbuf[wave + half][g * 4 + r];
        const float lB = lbuf[wave + half][g * 4 + r];
        const float M = fmaxf(mrow[r], mB);
        a[r] = __expf(mrow[r] - M);
        bt[r] = __expf(mB - M);
        lrow[r] = a[r] * lrow[r] + bt[r] * lB;
        mrow[r] = M;
      }
#pragma unroll
      for (int ht = 0; ht < 8; ++ht)
#pragma unroll
        for (int r = 0; r < 4; ++r)
          oacc[ht][r] =
              a[r] * oacc[ht][r] + bt[r] * Obuf[wave][g * 4 + r][ht * 16 + lr];
      if (lr == 0) {
#pragma unroll
        for (int r = 0; r < 4; ++r) {
          mbuf[wave][g * 4 + r] = mrow[r];
          lbuf[wave][g * 4 + r] = lrow[r];
        }
      }
    }
    __syncthreads();
  }

  // ---- epilogue: wave 0 normalizes and stores fp32 ----
  if (wave == 0) {
#pragma unroll
    for (int ht = 0; ht < 8; ++ht)
#pragma unroll
      for (int r = 0; r < 4; ++r) {
        const int qr = qr0 + g * 4 + r;
        out[((size_t)b * T_SEQ + qr) * H_DIM + ht * 16 + lr] =
            oacc[ht][r] / lrow[r];
      }
  }
}

extern "C" void kernel_launch(void* const* d_in, const int* in_sizes, int n_in,
                              void* d_out, int out_size, void* d_ws, size_t ws_size,
                              hipStream_t stream) {
  const float* x = (const float*)d_in[0];
  const float* Wq = (const float*)d_in[1];
  const float* Wk = (const float*)d_in[2];
  const float* Wv = (const float*)d_in[3];
  float* out = (float*)d_out;

  __hip_bfloat16* Wt = (__hip_bfloat16*)d_ws;
  __hip_bfloat16* qbuf = Wt + (size_t)3 * 128 * 1024;
  __hip_bfloat16* kbuf = qbuf + (size_t)NTOK * H_DIM;
  __hip_bfloat16* vbuf = kbuf + (size_t)NTOK * H_DIM;

  hipLaunchKernelGGL(prep_w_kernel, dim3(384), dim3(256), 0, stream, Wq, Wk, Wv, Wt);
  hipLaunchKernelGGL(proj_kernel, dim3(256), dim3(512), 0, stream, x, Wt, qbuf,
                     kbuf, vbuf);
  hipLaunchKernelGGL(attn_kernel, dim3(1024), dim3(512), 0, stream, qbuf, kbuf,
                     vbuf, out);
}

// Round 6
// 102.075 us; speedup vs baseline: 1.2476x; 1.2476x over previous
//
#include <hip/hip_runtime.h>
#include <hip/hip_bf16.h>
#include <stdint.h>

typedef float f32x4 __attribute__((ext_vector_type(4)));
typedef __bf16 bf16x8 __attribute__((ext_vector_type(8)));

#define T_SEQ 2048
#define D_EMB 1024
#define H_DIM 128
#define NBATCH 8
#define NTOK 16384  // NBATCH * T_SEQ

typedef __attribute__((address_space(3))) uint32_t lds_u32;
typedef const __attribute__((address_space(1))) uint32_t glb_u32;

// ---------------------------------------------------------------------------
// ws layout (bf16 elements):
//   Wt : [3][128][1024]   transposed weights (W^T), q|k|v
//   qb : [16384][128]     Q bf16
//   kb : [16384][128]     K bf16
//   vt : [8][128][2048]   V transposed per batch (PV B-frags contiguous)
// ---------------------------------------------------------------------------

__global__ __launch_bounds__(256) void prep_w_kernel(
    const float* __restrict__ Wq, const float* __restrict__ Wk,
    const float* __restrict__ Wv, __hip_bfloat16* __restrict__ Wt) {
  const int mat = blockIdx.x >> 7;   // 0..2
  const int h = blockIdx.x & 127;
  const float* W = (mat == 0) ? Wq : ((mat == 1) ? Wk : Wv);
  __hip_bfloat16* dst = Wt + (size_t)(mat * 128 + h) * D_EMB;
  for (int k = threadIdx.x; k < D_EMB; k += 256)
    dst[k] = __float2bfloat16(W[(size_t)k * H_DIM + h]);
}

// Projection GEMM, m97-style: C[16384,384] = xb * Wt^T.
// BM=64 x BN=384 (full N -> x read exactly once) x BK=64.
__global__ __launch_bounds__(512) void proj_kernel(
    const float* __restrict__ x, const __hip_bfloat16* __restrict__ Wt,
    __hip_bfloat16* __restrict__ qb, __hip_bfloat16* __restrict__ kb,
    __hip_bfloat16* __restrict__ vt) {
  __shared__ __align__(16) __hip_bfloat16 As[64 * 64];    // 8 KB
  __shared__ __align__(16) __hip_bfloat16 Bs[384 * 64];   // 48 KB
  const int tid = threadIdx.x;
  const int wave = tid >> 6;
  const int lane = tid & 63;
  const int g = lane >> 4;
  const int lr = lane & 15;
  const int m0 = blockIdx.x * 64;
  const int wc = wave * 48;

  f32x4 acc[4][3];
#pragma unroll
  for (int m = 0; m < 4; ++m)
#pragma unroll
    for (int n = 0; n < 3; ++n) acc[m][n] = f32x4{0.f, 0.f, 0.f, 0.f};

  const int arow = tid >> 3;        // 0..63
  const int acol = (tid & 7) * 8;   // 0..56
  const float* asrc = x + (size_t)(m0 + arow) * D_EMB + acol;
  __hip_bfloat16* adst = &As[arow * 64 + (acol ^ ((arow & 7) * 8))];

  for (int k0 = 0; k0 < D_EMB; k0 += 64) {
    __syncthreads();
#pragma unroll
    for (int i = 0; i < 6; ++i) {
      const int e = (i * 512 + tid) * 8;   // bf16 element index
      const int br = e >> 6;
      const int bc = e & 63;
      __builtin_amdgcn_global_load_lds(
          (glb_u32*)(uintptr_t)(Wt + (size_t)br * D_EMB + k0 + bc),
          (lds_u32*)(uintptr_t)(&Bs[e]), 16, 0, 0);
    }
    {
      const float4 f0 = *reinterpret_cast<const float4*>(asrc + k0);
      const float4 f1 = *reinterpret_cast<const float4*>(asrc + k0 + 4);
      union { bf16x8 v; __hip_bfloat16 h[8]; } u;
      u.h[0] = __float2bfloat16(f0.x);
      u.h[1] = __float2bfloat16(f0.y);
      u.h[2] = __float2bfloat16(f0.z);
      u.h[3] = __float2bfloat16(f0.w);
      u.h[4] = __float2bfloat16(f1.x);
      u.h[5] = __float2bfloat16(f1.y);
      u.h[6] = __float2bfloat16(f1.z);
      u.h[7] = __float2bfloat16(f1.w);
      *reinterpret_cast<bf16x8*>(adst) = u.v;
    }
    __syncthreads();
#pragma unroll
    for (int kk = 0; kk < 2; ++kk) {
      bf16x8 a[4];
#pragma unroll
      for (int m = 0; m < 4; ++m) {
        const int row = m * 16 + lr;
        a[m] = *reinterpret_cast<const bf16x8*>(
            &As[row * 64 + ((kk * 32 + g * 8) ^ ((row & 7) * 8))]);
      }
#pragma unroll
      for (int n = 0; n < 3; ++n) {
        bf16x8 b = *reinterpret_cast<const bf16x8*>(
            &Bs[(size_t)(wc + n * 16 + lr) * 64 + kk * 32 + g * 8]);
#pragma unroll
        for (int m = 0; m < 4; ++m)
          acc[m][n] =
              __builtin_amdgcn_mfma_f32_16x16x32_bf16(a[m], b, acc[m][n], 0, 0, 0);
      }
    }
  }

#pragma unroll
  for (int n = 0; n < 3; ++n) {
    const int ng = wc + n * 16 + lr;  // 0..383
    const int head = ng >> 7;         // 0:q 1:k 2:v
    const int h = ng & 127;
#pragma unroll
    for (int m = 0; m < 4; ++m) {
#pragma unroll
      for (int r = 0; r < 4; ++r) {
        const int row = m0 + m * 16 + g * 4 + r;  // global token
        const __hip_bfloat16 val = __float2bfloat16(acc[m][n][r]);
        if (head == 0) {
          qb[(size_t)row * H_DIM + h] = val;
        } else if (head == 1) {
          kb[(size_t)row * H_DIM + h] = val;
        } else {
          const int bi = row >> 11;
          const int t = row & (T_SEQ - 1);
          vt[((size_t)bi * H_DIM + h) * T_SEQ + t] = val;
        }
      }
    }
  }
}

// Flash attention with block-shared K/V LDS staging.
// grid = 256 (8 batches x 32 row-tiles of 64 q-rows), heavy tiles first.
// Block = 8 waves = 4 q-subtiles (16 rows) x 2 key-partitions (32 of 64 keys).
// Per 64-key round: all 512 threads stage K[64][128] + Vt[128][64] (32 KB)
// once via global_load_lds (double-buffered, one barrier/round); waves read
// XOR-swizzled fragments from LDS. 1-round kp-pair merge at the end.
__global__ __launch_bounds__(512) void attn_kernel(
    const __hip_bfloat16* __restrict__ qb, const __hip_bfloat16* __restrict__ kb,
    const __hip_bfloat16* __restrict__ vt, float* __restrict__ out) {
  __shared__ __align__(16) __hip_bfloat16 KV[2][16384];   // 64 KB: K(8192)+V(8192) per buf
  __shared__ __align__(16) __hip_bfloat16 Pl[8][16][40];  // 10 KB per-wave P tiles
  __shared__ float mbuf[8][16];
  __shared__ float lbuf[8][16];
  auto Obuf = reinterpret_cast<float(*)[16][132]>(&KV[0][0]);  // overlay, 33.8 KB

  const int tid = threadIdx.x;
  const int wave = tid >> 6;
  const int lane = tid & 63;
  const int g = lane >> 4;
  const int lr = lane & 15;
  const int qt = wave >> 1;   // q-subtile 0..3
  const int kp = wave & 1;    // key partition 0..1
  const int idx = blockIdx.x;
  const int b = idx & 7;                 // batch == XCD slot
  const int rt = 31 - (idx >> 3);        // heavy row-tiles dispatched first
  const int qr0b = rt * 64;              // block's first q row
  const int qrow0 = qr0b + qt * 16;      // wave's first q row
  const int nr = rt + 1;                 // 64-key rounds

  const __hip_bfloat16* qB = qb + (size_t)b * T_SEQ * H_DIM;
  const __hip_bfloat16* kB = kb + (size_t)b * T_SEQ * H_DIM;
  const __hip_bfloat16* vB = vt + (size_t)b * H_DIM * T_SEQ;

  // staging: K rows swizzled by 16B-group ^ (row&15); V rows by group ^ (h&7)
  auto stage = [&](__hip_bfloat16* buf, int s0) {
#pragma unroll
    for (int i = 0; i < 2; ++i) {
      const int u = tid + i * 512;
      const int row = u >> 4, grp = u & 15;
      __builtin_amdgcn_global_load_lds(
          (glb_u32*)(uintptr_t)(kB + (size_t)(s0 + row) * H_DIM +
                                ((grp ^ (row & 15)) * 8)),
          (lds_u32*)(uintptr_t)(buf + u * 8), 16, 0, 0);
    }
#pragma unroll
    for (int i = 0; i < 2; ++i) {
      const int u = tid + i * 512;
      const int h = u >> 3, grp = u & 7;
      __builtin_amdgcn_global_load_lds(
          (glb_u32*)(uintptr_t)(vB + (size_t)h * T_SEQ + s0 +
                                ((grp ^ (h & 7)) * 8)),
          (lds_u32*)(uintptr_t)(buf + 8192 + u * 8), 16, 0, 0);
    }
  };

  // Q fragments (global, once)
  bf16x8 qf[4];
#pragma unroll
  for (int kt = 0; kt < 4; ++kt)
    qf[kt] = *reinterpret_cast<const bf16x8*>(
        qB + (size_t)(qrow0 + lr) * H_DIM + kt * 32 + g * 8);

  f32x4 oacc[8];
#pragma unroll
  for (int i = 0; i < 8; ++i) oacc[i] = f32x4{0.f, 0.f, 0.f, 0.f};
  float mrow[4] = {-1e30f, -1e30f, -1e30f, -1e30f};
  float lrow[4] = {0.f, 0.f, 0.f, 0.f};
  const float scale = 0.08838834764831845f;  // 1/sqrt(128)

  __hip_bfloat16* bufA = &KV[0][0];
  __hip_bfloat16* bufB = &KV[1][0];
  stage(bufA, 0);
  __syncthreads();

  for (int r = 0; r < nr; ++r) {
    if (r + 1 < nr) stage(bufB, (r + 1) * 64);  // async prefetch next round
    const int s0 = r * 64;
    const bool active = (s0 + kp * 32) <= (qrow0 + 15);
    if (active) {
      // ---- QK^T from swizzled K tile ----
      f32x4 sacc[2];
      sacc[0] = f32x4{0.f, 0.f, 0.f, 0.f};
      sacc[1] = f32x4{0.f, 0.f, 0.f, 0.f};
#pragma unroll
      for (int nt = 0; nt < 2; ++nt) {
        const int kl = kp * 32 + nt * 16 + lr;  // key row in tile
        const __hip_bfloat16* kr = bufA + kl * 128;
#pragma unroll
        for (int kt = 0; kt < 4; ++kt) {
          bf16x8 kf = *reinterpret_cast<const bf16x8*>(
              kr + (((kt * 4 + g) ^ (kl & 15)) * 8));
          sacc[nt] =
              __builtin_amdgcn_mfma_f32_16x16x32_bf16(qf[kt], kf, sacc[nt], 0, 0, 0);
        }
      }
      // ---- V fragments early (LDS latency hides under softmax) ----
      bf16x8 vf[8];
#pragma unroll
      for (int ht = 0; ht < 8; ++ht) {
        const int h = ht * 16 + lr;
        vf[ht] = *reinterpret_cast<const bf16x8*>(
            bufA + 8192 + h * 64 + (((kp * 4 + g) ^ (h & 7)) * 8));
      }
      // ---- scale + causal mask ----
      float sv[2][4];
#pragma unroll
      for (int nt = 0; nt < 2; ++nt)
#pragma unroll
        for (int rr = 0; rr < 4; ++rr) {
          const int key = s0 + kp * 32 + nt * 16 + lr;
          const int qr = qrow0 + g * 4 + rr;
          const float s = sacc[nt][rr] * scale;
          sv[nt][rr] = (key > qr) ? -1e30f : s;
        }
      // ---- row max ----
      float pm[4];
#pragma unroll
      for (int rr = 0; rr < 4; ++rr) pm[rr] = fmaxf(sv[0][rr], sv[1][rr]);
#pragma unroll
      for (int m = 1; m < 16; m <<= 1)
#pragma unroll
        for (int rr = 0; rr < 4; ++rr)
          pm[rr] = fmaxf(pm[rr], __shfl_xor(pm[rr], m, 64));
      // ---- defer-rescale (T13) ----
      bool ok = true;
#pragma unroll
      for (int rr = 0; rr < 4; ++rr) ok = ok && (pm[rr] <= mrow[rr] + 8.f);
      if (!__all((int)ok)) {
#pragma unroll
        for (int rr = 0; rr < 4; ++rr) {
          const float mnew = fmaxf(mrow[rr], pm[rr]);
          const float corr = __expf(mrow[rr] - mnew);
          mrow[rr] = mnew;
          lrow[rr] *= corr;
#pragma unroll
          for (int ht = 0; ht < 8; ++ht) oacc[ht][rr] *= corr;
        }
      }
      // ---- P = exp(S - m), wave-private LDS tile, row-sum ----
      float rs[4];
#pragma unroll
      for (int rr = 0; rr < 4; ++rr) {
        const float p0 = __expf(sv[0][rr] - mrow[rr]);
        const float p1 = __expf(sv[1][rr] - mrow[rr]);
        Pl[wave][g * 4 + rr][lr] = __float2bfloat16(p0);
        Pl[wave][g * 4 + rr][16 + lr] = __float2bfloat16(p1);
        rs[rr] = p0 + p1;
      }
#pragma unroll
      for (int m = 1; m < 16; m <<= 1)
#pragma unroll
        for (int rr = 0; rr < 4; ++rr) rs[rr] += __shfl_xor(rs[rr], m, 64);
#pragma unroll
      for (int rr = 0; rr < 4; ++rr) lrow[rr] += rs[rr];
      // ---- PV ----
      bf16x8 pf = *reinterpret_cast<const bf16x8*>(&Pl[wave][lr][g * 8]);
#pragma unroll
      for (int ht = 0; ht < 8; ++ht)
        oacc[ht] =
            __builtin_amdgcn_mfma_f32_16x16x32_bf16(pf, vf[ht], oacc[ht], 0, 0, 0);
    }
    __syncthreads();  // drains prefetch (compiler waitcnt) + joins waves
    __hip_bfloat16* t = bufA; bufA = bufB; bufB = t;
  }

  // ---- kp-pair merge: kp=1 publishes, kp=0 combines & stores ----
  // (loop's final barrier ensures all KV reads done before Obuf overlay write)
  if (kp == 1) {
#pragma unroll
    for (int ht = 0; ht < 8; ++ht)
#pragma unroll
      for (int rr = 0; rr < 4; ++rr)
        Obuf[qt][g * 4 + rr][ht * 16 + lr] = oacc[ht][rr];
    if (lr == 0) {
#pragma unroll
      for (int rr = 0; rr < 4; ++rr) {
        mbuf[wave][g * 4 + rr] = mrow[rr];
        lbuf[wave][g * 4 + rr] = lrow[rr];
      }
    }
  }
  __syncthreads();
  if (kp == 0) {
#pragma unroll
    for (int rr = 0; rr < 4; ++rr) {
      const float mB = mbuf[wave + 1][g * 4 + rr];
      const float lB = lbuf[wave + 1][g * 4 + rr];
      const float M = fmaxf(mrow[rr], mB);
      const float a = __expf(mrow[rr] - M);
      const float bt = __expf(mB - M);
      lrow[rr] = a * lrow[rr] + bt * lB;
#pragma unroll
      for (int ht = 0; ht < 8; ++ht)
        oacc[ht][rr] =
            a * oacc[ht][rr] + bt * Obuf[qt][g * 4 + rr][ht * 16 + lr];
    }
#pragma unroll
    for (int ht = 0; ht < 8; ++ht)
#pragma unroll
      for (int rr = 0; rr < 4; ++rr) {
        const int qr = qrow0 + g * 4 + rr;
        out[((size_t)b * T_SEQ + qr) * H_DIM + ht * 16 + lr] =
            oacc[ht][rr] / lrow[rr];
      }
  }
}

extern "C" void kernel_launch(void* const* d_in, const int* in_sizes, int n_in,
                              void* d_out, int out_size, void* d_ws, size_t ws_size,
                              hipStream_t stream) {
  const float* x = (const float*)d_in[0];
  const float* Wq = (const float*)d_in[1];
  const float* Wk = (const float*)d_in[2];
  const float* Wv = (const float*)d_in[3];
  float* out = (float*)d_out;

  __hip_bfloat16* Wt = (__hip_bfloat16*)d_ws;
  __hip_bfloat16* qbuf = Wt + (size_t)3 * 128 * 1024;
  __hip_bfloat16* kbuf = qbuf + (size_t)NTOK * H_DIM;
  __hip_bfloat16* vbuf = kbuf + (size_t)NTOK * H_DIM;

  hipLaunchKernelGGL(prep_w_kernel, dim3(384), dim3(256), 0, stream, Wq, Wk, Wv, Wt);
  hipLaunchKernelGGL(proj_kernel, dim3(256), dim3(512), 0, stream, x, Wt, qbuf,
                     kbuf, vbuf);
  hipLaunchKernelGGL(attn_kernel, dim3(256), dim3(512), 0, stream, qbuf, kbuf,
                     vbuf, out);
}

// Round 7
// 80.530 us; speedup vs baseline: 1.5814x; 1.2675x over previous
//
#include <hip/hip_runtime.h>
#include <hip/hip_bf16.h>
#include <stdint.h>

typedef float f32x4 __attribute__((ext_vector_type(4)));
typedef __bf16 bf16x8 __attribute__((ext_vector_type(8)));

#define T_SEQ 2048
#define D_EMB 1024
#define H_DIM 128
#define NBATCH 8
#define NTOK 16384  // NBATCH * T_SEQ

typedef __attribute__((address_space(3))) uint32_t lds_u32;
typedef const __attribute__((address_space(1))) uint32_t glb_u32;

// DPP cross-lane (within 16-lane row): VALU-latency replacement for shfl_xor
#define DPPF(x, ctrl)                                                    \
  __int_as_float(__builtin_amdgcn_update_dpp(                            \
      0, __float_as_int(x), (ctrl), 0xF, 0xF, true))
// ctrl: 0xB1 = quad_perm[1,0,3,2] (xor1), 0x4E = quad_perm[2,3,0,1] (xor2),
//       0x141 = row_half_mirror (combines quads), 0x140 = row_mirror (halves)

// ---------------------------------------------------------------------------
// ws layout:
//   bf16: Wt[3][128][1024] | qb[16384][128] | kb[16384][128] | vt[8][128][2048]
//   f32 : PA_O[8][16][64][128] PA_ml[8][16][64][2] PB_O[...] PB_ml[...]
// ---------------------------------------------------------------------------

__global__ __launch_bounds__(256) void prep_w_kernel(
    const float* __restrict__ Wq, const float* __restrict__ Wk,
    const float* __restrict__ Wv, __hip_bfloat16* __restrict__ Wt) {
  const int mat = blockIdx.x >> 7;   // 0..2
  const int h = blockIdx.x & 127;
  const float* W = (mat == 0) ? Wq : ((mat == 1) ? Wk : Wv);
  __hip_bfloat16* dst = Wt + (size_t)(mat * 128 + h) * D_EMB;
  for (int k = threadIdx.x; k < D_EMB; k += 256)
    dst[k] = __float2bfloat16(W[(size_t)k * H_DIM + h]);
}

// Projection GEMM, m97-style (unchanged from R3).
__global__ __launch_bounds__(512) void proj_kernel(
    const float* __restrict__ x, const __hip_bfloat16* __restrict__ Wt,
    __hip_bfloat16* __restrict__ qb, __hip_bfloat16* __restrict__ kb,
    __hip_bfloat16* __restrict__ vt) {
  __shared__ __align__(16) __hip_bfloat16 As[64 * 64];    // 8 KB
  __shared__ __align__(16) __hip_bfloat16 Bs[384 * 64];   // 48 KB
  const int tid = threadIdx.x;
  const int wave = tid >> 6;
  const int lane = tid & 63;
  const int g = lane >> 4;
  const int lr = lane & 15;
  const int m0 = blockIdx.x * 64;
  const int wc = wave * 48;

  f32x4 acc[4][3];
#pragma unroll
  for (int m = 0; m < 4; ++m)
#pragma unroll
    for (int n = 0; n < 3; ++n) acc[m][n] = f32x4{0.f, 0.f, 0.f, 0.f};

  const int arow = tid >> 3;        // 0..63
  const int acol = (tid & 7) * 8;   // 0..56
  const float* asrc = x + (size_t)(m0 + arow) * D_EMB + acol;
  __hip_bfloat16* adst = &As[arow * 64 + (acol ^ ((arow & 7) * 8))];

  for (int k0 = 0; k0 < D_EMB; k0 += 64) {
    __syncthreads();
#pragma unroll
    for (int i = 0; i < 6; ++i) {
      const int e = (i * 512 + tid) * 8;   // bf16 element index
      const int br = e >> 6;
      const int bc = e & 63;
      __builtin_amdgcn_global_load_lds(
          (glb_u32*)(uintptr_t)(Wt + (size_t)br * D_EMB + k0 + bc),
          (lds_u32*)(uintptr_t)(&Bs[e]), 16, 0, 0);
    }
    {
      const float4 f0 = *reinterpret_cast<const float4*>(asrc + k0);
      const float4 f1 = *reinterpret_cast<const float4*>(asrc + k0 + 4);
      union { bf16x8 v; __hip_bfloat16 h[8]; } u;
      u.h[0] = __float2bfloat16(f0.x);
      u.h[1] = __float2bfloat16(f0.y);
      u.h[2] = __float2bfloat16(f0.z);
      u.h[3] = __float2bfloat16(f0.w);
      u.h[4] = __float2bfloat16(f1.x);
      u.h[5] = __float2bfloat16(f1.y);
      u.h[6] = __float2bfloat16(f1.z);
      u.h[7] = __float2bfloat16(f1.w);
      *reinterpret_cast<bf16x8*>(adst) = u.v;
    }
    __syncthreads();
#pragma unroll
    for (int kk = 0; kk < 2; ++kk) {
      bf16x8 a[4];
#pragma unroll
      for (int m = 0; m < 4; ++m) {
        const int row = m * 16 + lr;
        a[m] = *reinterpret_cast<const bf16x8*>(
            &As[row * 64 + ((kk * 32 + g * 8) ^ ((row & 7) * 8))]);
      }
#pragma unroll
      for (int n = 0; n < 3; ++n) {
        bf16x8 b = *reinterpret_cast<const bf16x8*>(
            &Bs[(size_t)(wc + n * 16 + lr) * 64 + kk * 32 + g * 8]);
#pragma unroll
        for (int m = 0; m < 4; ++m)
          acc[m][n] =
              __builtin_amdgcn_mfma_f32_16x16x32_bf16(a[m], b, acc[m][n], 0, 0, 0);
      }
    }
  }

#pragma unroll
  for (int n = 0; n < 3; ++n) {
    const int ng = wc + n * 16 + lr;  // 0..383
    const int head = ng >> 7;         // 0:q 1:k 2:v
    const int h = ng & 127;
#pragma unroll
    for (int m = 0; m < 4; ++m) {
#pragma unroll
      for (int r = 0; r < 4; ++r) {
        const int row = m0 + m * 16 + g * 4 + r;  // global token
        const __hip_bfloat16 val = __float2bfloat16(acc[m][n][r]);
        if (head == 0) {
          qb[(size_t)row * H_DIM + h] = val;
        } else if (head == 1) {
          kb[(size_t)row * H_DIM + h] = val;
        } else {
          const int bi = row >> 11;
          const int t = row & (T_SEQ - 1);
          vt[((size_t)bi * H_DIM + h) * T_SEQ + t] = val;
        }
      }
    }
  }
}

// Flash attention, LDS-shared K/V + causal pairing + DPP softmax reductions.
// grid = 256: b = idx&7, u = idx>>3 (0..31).
//  u<16 (block A): light tile u (full, direct out) then heavy tile 31-u
//                  rounds 0..15-u (partial A).  17 rounds total.
//  u>=16 (block B): heavy tile 31-(u-16), rounds 16-(u-16)..31-(u-16)
//                  (partial B).  16 rounds.
// Block = 8 waves = 4 q-subtiles(16 rows) x 2 key-partitions(32 of 64 keys).
__global__ __launch_bounds__(512) void attn_kernel(
    const __hip_bfloat16* __restrict__ qb, const __hip_bfloat16* __restrict__ kb,
    const __hip_bfloat16* __restrict__ vt, float* __restrict__ out,
    float* __restrict__ PA_O, float* __restrict__ PA_ml,
    float* __restrict__ PB_O, float* __restrict__ PB_ml) {
  __shared__ __align__(16) __hip_bfloat16 KV[2][16384];   // 64 KB
  __shared__ __align__(16) __hip_bfloat16 Pl[8][16][40];  // 10 KB
  __shared__ float Obuf[4][16][132];                      // 33.8 KB
  __shared__ float mbuf[8][16];
  __shared__ float lbuf[8][16];

  const int tid = threadIdx.x;
  const int wave = tid >> 6;
  const int lane = tid & 63;
  const int g = lane >> 4;
  const int lr = lane & 15;
  const int qt = wave >> 1;   // q-subtile 0..3
  const int kp = wave & 1;    // key partition 0..1
  const int idx = blockIdx.x;
  const int b = idx & 7;
  const int u = idx >> 3;     // 0..31

  const __hip_bfloat16* qB = qb + (size_t)b * T_SEQ * H_DIM;
  const __hip_bfloat16* kB = kb + (size_t)b * T_SEQ * H_DIM;
  const __hip_bfloat16* vB = vt + (size_t)b * H_DIM * T_SEQ;
  const float scale = 0.08838834764831845f;  // 1/sqrt(128)

  auto stage = [&](__hip_bfloat16* buf, int s0) {
#pragma unroll
    for (int i = 0; i < 2; ++i) {
      const int uu = tid + i * 512;
      const int row = uu >> 4, grp = uu & 15;
      __builtin_amdgcn_global_load_lds(
          (glb_u32*)(uintptr_t)(kB + (size_t)(s0 + row) * H_DIM +
                                ((grp ^ (row & 15)) * 8)),
          (lds_u32*)(uintptr_t)(buf + uu * 8), 16, 0, 0);
    }
#pragma unroll
    for (int i = 0; i < 2; ++i) {
      const int uu = tid + i * 512;
      const int h = uu >> 3, grp = uu & 7;
      __builtin_amdgcn_global_load_lds(
          (glb_u32*)(uintptr_t)(vB + (size_t)h * T_SEQ + s0 +
                                ((grp ^ (h & 7)) * 8)),
          (lds_u32*)(uintptr_t)(buf + 8192 + uu * 8), 16, 0, 0);
    }
  };

  // mode: 0 = direct out, 1 = partial A, 2 = partial B
  auto process = [&](int tile, int rr0, int rr1, int mode) {
    const int qrow0 = tile * 64 + qt * 16;
    bf16x8 qf[4];
#pragma unroll
    for (int kt = 0; kt < 4; ++kt)
      qf[kt] = *reinterpret_cast<const bf16x8*>(
          qB + (size_t)(qrow0 + lr) * H_DIM + kt * 32 + g * 8);

    f32x4 oacc[8];
#pragma unroll
    for (int i = 0; i < 8; ++i) oacc[i] = f32x4{0.f, 0.f, 0.f, 0.f};
    float mrow[4] = {-1e30f, -1e30f, -1e30f, -1e30f};
    float lrow[4] = {0.f, 0.f, 0.f, 0.f};

    __hip_bfloat16* bufA = &KV[0][0];
    __hip_bfloat16* bufB = &KV[1][0];
    stage(bufA, rr0 * 64);
    __syncthreads();

    for (int r = rr0; r <= rr1; ++r) {
      if (r < rr1) stage(bufB, (r + 1) * 64);
      const int s0 = r * 64;
      const bool active = (s0 + kp * 32) <= (qrow0 + 15);
      if (active) {
        // ---- QK^T from swizzled K tile ----
        f32x4 sacc[2];
        sacc[0] = f32x4{0.f, 0.f, 0.f, 0.f};
        sacc[1] = f32x4{0.f, 0.f, 0.f, 0.f};
#pragma unroll
        for (int nt = 0; nt < 2; ++nt) {
          const int kl = kp * 32 + nt * 16 + lr;
          const __hip_bfloat16* kr = bufA + kl * 128;
#pragma unroll
          for (int kt = 0; kt < 4; ++kt) {
            bf16x8 kf = *reinterpret_cast<const bf16x8*>(
                kr + (((kt * 4 + g) ^ (kl & 15)) * 8));
            sacc[nt] = __builtin_amdgcn_mfma_f32_16x16x32_bf16(qf[kt], kf,
                                                               sacc[nt], 0, 0, 0);
          }
        }
        // ---- V fragments early (LDS latency hides under softmax) ----
        bf16x8 vf[8];
#pragma unroll
        for (int ht = 0; ht < 8; ++ht) {
          const int h = ht * 16 + lr;
          vf[ht] = *reinterpret_cast<const bf16x8*>(
              bufA + 8192 + h * 64 + (((kp * 4 + g) ^ (h & 7)) * 8));
        }
        // ---- scale + causal mask ----
        float sv[2][4];
#pragma unroll
        for (int nt = 0; nt < 2; ++nt)
#pragma unroll
          for (int rr = 0; rr < 4; ++rr) {
            const int key = s0 + kp * 32 + nt * 16 + lr;
            const int qr = qrow0 + g * 4 + rr;
            const float s = sacc[nt][rr] * scale;
            sv[nt][rr] = (key > qr) ? -1e30f : s;
          }
        // ---- row max via DPP (VALU latency, no LDS round-trips) ----
        float pm[4];
#pragma unroll
        for (int rr = 0; rr < 4; ++rr) pm[rr] = fmaxf(sv[0][rr], sv[1][rr]);
#pragma unroll
        for (int rr = 0; rr < 4; ++rr) {
          pm[rr] = fmaxf(pm[rr], DPPF(pm[rr], 0xB1));
          pm[rr] = fmaxf(pm[rr], DPPF(pm[rr], 0x4E));
          pm[rr] = fmaxf(pm[rr], DPPF(pm[rr], 0x141));
          pm[rr] = fmaxf(pm[rr], DPPF(pm[rr], 0x140));
        }
        // ---- defer-rescale (T13) ----
        bool ok = true;
#pragma unroll
        for (int rr = 0; rr < 4; ++rr) ok = ok && (pm[rr] <= mrow[rr] + 8.f);
        if (!__all((int)ok)) {
#pragma unroll
          for (int rr = 0; rr < 4; ++rr) {
            const float mnew = fmaxf(mrow[rr], pm[rr]);
            const float corr = __expf(mrow[rr] - mnew);
            mrow[rr] = mnew;
            lrow[rr] *= corr;
#pragma unroll
            for (int ht = 0; ht < 8; ++ht) oacc[ht][rr] *= corr;
          }
        }
        // ---- P = exp(S - m), wave-private LDS tile, row-sum via DPP ----
        float rs[4];
#pragma unroll
        for (int rr = 0; rr < 4; ++rr) {
          const float p0 = __expf(sv[0][rr] - mrow[rr]);
          const float p1 = __expf(sv[1][rr] - mrow[rr]);
          Pl[wave][g * 4 + rr][lr] = __float2bfloat16(p0);
          Pl[wave][g * 4 + rr][16 + lr] = __float2bfloat16(p1);
          rs[rr] = p0 + p1;
        }
#pragma unroll
        for (int rr = 0; rr < 4; ++rr) {
          rs[rr] += DPPF(rs[rr], 0xB1);
          rs[rr] += DPPF(rs[rr], 0x4E);
          rs[rr] += DPPF(rs[rr], 0x141);
          rs[rr] += DPPF(rs[rr], 0x140);
        }
#pragma unroll
        for (int rr = 0; rr < 4; ++rr) lrow[rr] += rs[rr];
        // ---- PV ----
        bf16x8 pf = *reinterpret_cast<const bf16x8*>(&Pl[wave][lr][g * 8]);
#pragma unroll
        for (int ht = 0; ht < 8; ++ht)
          oacc[ht] = __builtin_amdgcn_mfma_f32_16x16x32_bf16(pf, vf[ht],
                                                             oacc[ht], 0, 0, 0);
      }
      __syncthreads();
      __hip_bfloat16* t = bufA; bufA = bufB; bufB = t;
    }

    // ---- kp-pair merge ----
    if (kp == 1) {
#pragma unroll
      for (int ht = 0; ht < 8; ++ht)
#pragma unroll
        for (int rr = 0; rr < 4; ++rr)
          Obuf[qt][g * 4 + rr][ht * 16 + lr] = oacc[ht][rr];
      if (lr == 0) {
#pragma unroll
        for (int rr = 0; rr < 4; ++rr) {
          mbuf[wave][g * 4 + rr] = mrow[rr];
          lbuf[wave][g * 4 + rr] = lrow[rr];
        }
      }
    }
    __syncthreads();
    if (kp == 0) {
#pragma unroll
      for (int rr = 0; rr < 4; ++rr) {
        const float mB = mbuf[wave + 1][g * 4 + rr];
        const float lB = lbuf[wave + 1][g * 4 + rr];
        const float M = fmaxf(mrow[rr], mB);
        const float a = __expf(mrow[rr] - M);
        const float bt = __expf(mB - M);
        lrow[rr] = a * lrow[rr] + bt * lB;
        mrow[rr] = M;
#pragma unroll
        for (int ht = 0; ht < 8; ++ht)
          oacc[ht][rr] =
              a * oacc[ht][rr] + bt * Obuf[qt][g * 4 + rr][ht * 16 + lr];
      }
      if (mode == 0) {
#pragma unroll
        for (int ht = 0; ht < 8; ++ht)
#pragma unroll
          for (int rr = 0; rr < 4; ++rr) {
            const int qr = qrow0 + g * 4 + rr;
            out[((size_t)b * T_SEQ + qr) * H_DIM + ht * 16 + lr] =
                oacc[ht][rr] / lrow[rr];
          }
      } else {
        float* PO = (mode == 1) ? PA_O : PB_O;
        float* Pm = (mode == 1) ? PA_ml : PB_ml;
        const int slot = tile - 16;
#pragma unroll
        for (int rr = 0; rr < 4; ++rr) {
          const size_t pr = (size_t)(b * 16 + slot) * 64 + qt * 16 + g * 4 + rr;
#pragma unroll
          for (int ht = 0; ht < 8; ++ht)
            PO[pr * 128 + ht * 16 + lr] = oacc[ht][rr];
          if (lr == 0) {
            Pm[pr * 2 + 0] = mrow[rr];
            Pm[pr * 2 + 1] = lrow[rr];
          }
        }
      }
    }
    __syncthreads();
  };

  if (u < 16) {
    process(u, 0, u, 0);                 // light tile, full, direct out
    process(31 - u, 0, 15 - u, 1);       // heavy tile, early keys, partial A
  } else {
    const int v = u - 16;
    process(31 - v, 16 - v, 31 - v, 2);  // heavy tile, late keys, partial B
  }
}

// Merge the two partials of each heavy tile. grid = 8*16 = 128 blocks.
__global__ __launch_bounds__(256) void combine_kernel(
    const float* __restrict__ PA_O, const float* __restrict__ PA_ml,
    const float* __restrict__ PB_O, const float* __restrict__ PB_ml,
    float* __restrict__ out) {
  const int b = blockIdx.x >> 4;
  const int s = blockIdx.x & 15;
  const int tid = threadIdx.x;
  const int row = tid >> 2;          // 0..63
  const int c0 = (tid & 3) * 32;
  const size_t pr = (size_t)(b * 16 + s) * 64 + row;
  const float mA = PA_ml[pr * 2], lA = PA_ml[pr * 2 + 1];
  const float mB = PB_ml[pr * 2], lB = PB_ml[pr * 2 + 1];
  const float M = fmaxf(mA, mB);
  const float a = __expf(mA - M), bb = __expf(mB - M);
  const float inv = 1.f / (a * lA + bb * lB);
  const float* oa = PA_O + pr * 128 + c0;
  const float* ob = PB_O + pr * 128 + c0;
  float* op = out + ((size_t)b * T_SEQ + (16 + s) * 64 + row) * H_DIM + c0;
#pragma unroll
  for (int i = 0; i < 32; i += 4) {
    const float4 x = *reinterpret_cast<const float4*>(oa + i);
    const float4 y = *reinterpret_cast<const float4*>(ob + i);
    float4 z;
    z.x = (a * x.x + bb * y.x) * inv;
    z.y = (a * x.y + bb * y.y) * inv;
    z.z = (a * x.z + bb * y.z) * inv;
    z.w = (a * x.w + bb * y.w) * inv;
    *reinterpret_cast<float4*>(op + i) = z;
  }
}

extern "C" void kernel_launch(void* const* d_in, const int* in_sizes, int n_in,
                              void* d_out, int out_size, void* d_ws, size_t ws_size,
                              hipStream_t stream) {
  const float* x = (const float*)d_in[0];
  const float* Wq = (const float*)d_in[1];
  const float* Wk = (const float*)d_in[2];
  const float* Wv = (const float*)d_in[3];
  float* out = (float*)d_out;

  __hip_bfloat16* Wt = (__hip_bfloat16*)d_ws;
  __hip_bfloat16* qbuf = Wt + (size_t)3 * 128 * 1024;
  __hip_bfloat16* kbuf = qbuf + (size_t)NTOK * H_DIM;
  __hip_bfloat16* vbuf = kbuf + (size_t)NTOK * H_DIM;
  float* fbase = (float*)(vbuf + (size_t)NBATCH * H_DIM * T_SEQ);
  float* PA_O = fbase;                       // 8*16*64*128 = 1,048,576 f
  float* PA_ml = PA_O + (size_t)1048576;     // 16,384 f
  float* PB_O = PA_ml + 16384;
  float* PB_ml = PB_O + (size_t)1048576;

  hipLaunchKernelGGL(prep_w_kernel, dim3(384), dim3(256), 0, stream, Wq, Wk, Wv, Wt);
  hipLaunchKernelGGL(proj_kernel, dim3(256), dim3(512), 0, stream, x, Wt, qbuf,
                     kbuf, vbuf);
  hipLaunchKernelGGL(attn_kernel, dim3(256), dim3(512), 0, stream, qbuf, kbuf,
                     vbuf, out, PA_O, PA_ml, PB_O, PB_ml);
  hipLaunchKernelGGL(combine_kernel, dim3(128), dim3(256), 0, stream, PA_O,
                     PA_ml, PB_O, PB_ml, out);
}

// Round 8
// 71.615 us; speedup vs baseline: 1.7782x; 1.1245x over previous
//
#include <hip/hip_runtime.h>
#include <hip/hip_bf16.h>
#include <stdint.h>

typedef float f32x4 __attribute__((ext_vector_type(4)));
typedef __bf16 bf16x8 __attribute__((ext_vector_type(8)));

#define T_SEQ 2048
#define D_EMB 1024
#define H_DIM 128
#define NBATCH 8
#define NTOK 16384  // NBATCH * T_SEQ

typedef __attribute__((address_space(3))) uint32_t lds_u32;
typedef const __attribute__((address_space(1))) uint32_t glb_u32;

// DPP cross-lane (within 16-lane row): VALU-latency replacement for shfl_xor
#define DPPF(x, ctrl)                                                    \
  __int_as_float(__builtin_amdgcn_update_dpp(                            \
      0, __float_as_int(x), (ctrl), 0xF, 0xF, true))

// ---------------------------------------------------------------------------
// ws layout:
//   bf16: Wt[3][128][1024] | qb[16384][128] | kb[16384][128] | vt[8][128][2048]
//   f32 : PA_O[8][16][64][128] PA_ml[8][16][64][2] PB_O[...] PB_ml[...]
// ---------------------------------------------------------------------------

__global__ __launch_bounds__(256) void prep_w_kernel(
    const float* __restrict__ Wq, const float* __restrict__ Wk,
    const float* __restrict__ Wv, __hip_bfloat16* __restrict__ Wt) {
  const int mat = blockIdx.x >> 7;   // 0..2
  const int h = blockIdx.x & 127;
  const float* W = (mat == 0) ? Wq : ((mat == 1) ? Wk : Wv);
  __hip_bfloat16* dst = Wt + (size_t)(mat * 128 + h) * D_EMB;
  for (int k = threadIdx.x; k < D_EMB; k += 256)
    dst[k] = __float2bfloat16(W[(size_t)k * H_DIM + h]);
}

// Projection GEMM: C[16384,384] = x(bf16) * Wt^T, BM=64 BN=384(full) BK=64.
// 2-phase double-buffered pipeline, one barrier/step:
//   loop { issue x-loads(k+1) + B-stage(k+1)->buf^1; compute(buf);
//          cvt+ds_write A(k+1); barrier; swap }
// B staged with PRE-SWIZZLED global source (chunk ^= row&7) so the linear-LDS
// constraint of global_load_lds still yields conflict-free swizzled reads.
__global__ __launch_bounds__(512) void proj_kernel(
    const float* __restrict__ x, const __hip_bfloat16* __restrict__ Wt,
    __hip_bfloat16* __restrict__ qb, __hip_bfloat16* __restrict__ kb,
    __hip_bfloat16* __restrict__ vt) {
  __shared__ __align__(16) __hip_bfloat16 As[2][64 * 64];    // 16 KB
  __shared__ __align__(16) __hip_bfloat16 Bs[2][384 * 64];   // 96 KB
  const int tid = threadIdx.x;
  const int wave = tid >> 6;
  const int lane = tid & 63;
  const int g = lane >> 4;
  const int lr = lane & 15;
  const int m0 = blockIdx.x * 64;
  const int wc = wave * 48;   // 48 % 8 == 0 -> (wc+n*16+lr)&7 == lr&7

  f32x4 acc[4][3];
#pragma unroll
  for (int m = 0; m < 4; ++m)
#pragma unroll
    for (int n = 0; n < 3; ++n) acc[m][n] = f32x4{0.f, 0.f, 0.f, 0.f};

  const int arow = tid >> 3;        // 0..63
  const int acol = (tid & 7) * 8;   // 0..56
  const float* asrc = x + (size_t)(m0 + arow) * D_EMB + acol;

  auto stageB = [&](int buf, int k0) {
#pragma unroll
    for (int i = 0; i < 6; ++i) {
      const int u = i * 512 + tid;   // 16B-unit index, 0..3071
      const int row = u >> 3;        // 0..383
      const int chunk = u & 7;       // 8 chunks of 8 bf16 per row
      __builtin_amdgcn_global_load_lds(
          (glb_u32*)(uintptr_t)(Wt + (size_t)row * D_EMB + k0 +
                                ((chunk ^ (row & 7)) * 8)),
          (lds_u32*)(uintptr_t)(&Bs[buf][row * 64 + chunk * 8]), 16, 0, 0);
    }
  };
  auto writeA = [&](int buf, float4 f0, float4 f1) {
    union { bf16x8 v; __hip_bfloat16 h[8]; } u;
    u.h[0] = __float2bfloat16(f0.x);
    u.h[1] = __float2bfloat16(f0.y);
    u.h[2] = __float2bfloat16(f0.z);
    u.h[3] = __float2bfloat16(f0.w);
    u.h[4] = __float2bfloat16(f1.x);
    u.h[5] = __float2bfloat16(f1.y);
    u.h[6] = __float2bfloat16(f1.z);
    u.h[7] = __float2bfloat16(f1.w);
    *reinterpret_cast<bf16x8*>(
        &As[buf][arow * 64 + (acol ^ ((arow & 7) * 8))]) = u.v;
  };
  auto compute = [&](int buf) {
#pragma unroll
    for (int kk = 0; kk < 2; ++kk) {
      bf16x8 a[4];
#pragma unroll
      for (int m = 0; m < 4; ++m) {
        const int row = m * 16 + lr;
        a[m] = *reinterpret_cast<const bf16x8*>(
            &As[buf][row * 64 + ((kk * 32 + g * 8) ^ ((row & 7) * 8))]);
      }
#pragma unroll
      for (int n = 0; n < 3; ++n) {
        const int row = wc + n * 16 + lr;
        bf16x8 b = *reinterpret_cast<const bf16x8*>(
            &Bs[buf][row * 64 + (((kk * 4 + g) ^ (row & 7)) * 8)]);
#pragma unroll
        for (int m = 0; m < 4; ++m)
          acc[m][n] =
              __builtin_amdgcn_mfma_f32_16x16x32_bf16(a[m], b, acc[m][n], 0, 0, 0);
      }
    }
  };

  // ---- prologue: stage k=0 into buf 0 ----
  {
    float4 f0 = *reinterpret_cast<const float4*>(asrc);
    float4 f1 = *reinterpret_cast<const float4*>(asrc + 4);
    stageB(0, 0);
    writeA(0, f0, f1);
  }
  __syncthreads();

  int cur = 0;
  for (int k = 0; k < 16; ++k) {
    float4 f0, f1;
    if (k < 15) {
      const int k0n = (k + 1) * 64;
      f0 = *reinterpret_cast<const float4*>(asrc + k0n);      // HBM issue early
      f1 = *reinterpret_cast<const float4*>(asrc + k0n + 4);
      stageB(cur ^ 1, k0n);                                   // L2 -> LDS async
    }
    compute(cur);              // MFMA hides the load latency
    if (k < 15) writeA(cur ^ 1, f0, f1);  // x waitcnt lands here, post-compute
    __syncthreads();           // drains vmcnt (B-stage) + lgkm (A-write)
    cur ^= 1;
  }

  // ---- store: C layout col=lane&15, row=(lane>>4)*4+reg ----
#pragma unroll
  for (int n = 0; n < 3; ++n) {
    const int ng = wc + n * 16 + lr;  // 0..383
    const int head = ng >> 7;         // 0:q 1:k 2:v
    const int h = ng & 127;
#pragma unroll
    for (int m = 0; m < 4; ++m) {
#pragma unroll
      for (int r = 0; r < 4; ++r) {
        const int row = m0 + m * 16 + g * 4 + r;  // global token
        const __hip_bfloat16 val = __float2bfloat16(acc[m][n][r]);
        if (head == 0) {
          qb[(size_t)row * H_DIM + h] = val;
        } else if (head == 1) {
          kb[(size_t)row * H_DIM + h] = val;
        } else {
          const int bi = row >> 11;
          const int t = row & (T_SEQ - 1);
          vt[((size_t)bi * H_DIM + h) * T_SEQ + t] = val;
        }
      }
    }
  }
}

// Flash attention, LDS-shared K/V + causal pairing + DPP softmax reductions.
// (unchanged from R7)
__global__ __launch_bounds__(512) void attn_kernel(
    const __hip_bfloat16* __restrict__ qb, const __hip_bfloat16* __restrict__ kb,
    const __hip_bfloat16* __restrict__ vt, float* __restrict__ out,
    float* __restrict__ PA_O, float* __restrict__ PA_ml,
    float* __restrict__ PB_O, float* __restrict__ PB_ml) {
  __shared__ __align__(16) __hip_bfloat16 KV[2][16384];   // 64 KB
  __shared__ __align__(16) __hip_bfloat16 Pl[8][16][40];  // 10 KB
  __shared__ float Obuf[4][16][132];                      // 33.8 KB
  __shared__ float mbuf[8][16];
  __shared__ float lbuf[8][16];

  const int tid = threadIdx.x;
  const int wave = tid >> 6;
  const int lane = tid & 63;
  const int g = lane >> 4;
  const int lr = lane & 15;
  const int qt = wave >> 1;   // q-subtile 0..3
  const int kp = wave & 1;    // key partition 0..1
  const int idx = blockIdx.x;
  const int b = idx & 7;
  const int u = idx >> 3;     // 0..31

  const __hip_bfloat16* qB = qb + (size_t)b * T_SEQ * H_DIM;
  const __hip_bfloat16* kB = kb + (size_t)b * T_SEQ * H_DIM;
  const __hip_bfloat16* vB = vt + (size_t)b * H_DIM * T_SEQ;
  const float scale = 0.08838834764831845f;  // 1/sqrt(128)

  auto stage = [&](__hip_bfloat16* buf, int s0) {
#pragma unroll
    for (int i = 0; i < 2; ++i) {
      const int uu = tid + i * 512;
      const int row = uu >> 4, grp = uu & 15;
      __builtin_amdgcn_global_load_lds(
          (glb_u32*)(uintptr_t)(kB + (size_t)(s0 + row) * H_DIM +
                                ((grp ^ (row & 15)) * 8)),
          (lds_u32*)(uintptr_t)(buf + uu * 8), 16, 0, 0);
    }
#pragma unroll
    for (int i = 0; i < 2; ++i) {
      const int uu = tid + i * 512;
      const int h = uu >> 3, grp = uu & 7;
      __builtin_amdgcn_global_load_lds(
          (glb_u32*)(uintptr_t)(vB + (size_t)h * T_SEQ + s0 +
                                ((grp ^ (h & 7)) * 8)),
          (lds_u32*)(uintptr_t)(buf + 8192 + uu * 8), 16, 0, 0);
    }
  };

  // mode: 0 = direct out, 1 = partial A, 2 = partial B
  auto process = [&](int tile, int rr0, int rr1, int mode) {
    const int qrow0 = tile * 64 + qt * 16;
    bf16x8 qf[4];
#pragma unroll
    for (int kt = 0; kt < 4; ++kt)
      qf[kt] = *reinterpret_cast<const bf16x8*>(
          qB + (size_t)(qrow0 + lr) * H_DIM + kt * 32 + g * 8);

    f32x4 oacc[8];
#pragma unroll
    for (int i = 0; i < 8; ++i) oacc[i] = f32x4{0.f, 0.f, 0.f, 0.f};
    float mrow[4] = {-1e30f, -1e30f, -1e30f, -1e30f};
    float lrow[4] = {0.f, 0.f, 0.f, 0.f};

    __hip_bfloat16* bufA = &KV[0][0];
    __hip_bfloat16* bufB = &KV[1][0];
    stage(bufA, rr0 * 64);
    __syncthreads();

    for (int r = rr0; r <= rr1; ++r) {
      if (r < rr1) stage(bufB, (r + 1) * 64);
      const int s0 = r * 64;
      const bool active = (s0 + kp * 32) <= (qrow0 + 15);
      if (active) {
        // ---- QK^T from swizzled K tile ----
        f32x4 sacc[2];
        sacc[0] = f32x4{0.f, 0.f, 0.f, 0.f};
        sacc[1] = f32x4{0.f, 0.f, 0.f, 0.f};
#pragma unroll
        for (int nt = 0; nt < 2; ++nt) {
          const int kl = kp * 32 + nt * 16 + lr;
          const __hip_bfloat16* kr = bufA + kl * 128;
#pragma unroll
          for (int kt = 0; kt < 4; ++kt) {
            bf16x8 kf = *reinterpret_cast<const bf16x8*>(
                kr + (((kt * 4 + g) ^ (kl & 15)) * 8));
            sacc[nt] = __builtin_amdgcn_mfma_f32_16x16x32_bf16(qf[kt], kf,
                                                               sacc[nt], 0, 0, 0);
          }
        }
        // ---- V fragments early (LDS latency hides under softmax) ----
        bf16x8 vf[8];
#pragma unroll
        for (int ht = 0; ht < 8; ++ht) {
          const int h = ht * 16 + lr;
          vf[ht] = *reinterpret_cast<const bf16x8*>(
              bufA + 8192 + h * 64 + (((kp * 4 + g) ^ (h & 7)) * 8));
        }
        // ---- scale + causal mask ----
        float sv[2][4];
#pragma unroll
        for (int nt = 0; nt < 2; ++nt)
#pragma unroll
          for (int rr = 0; rr < 4; ++rr) {
            const int key = s0 + kp * 32 + nt * 16 + lr;
            const int qr = qrow0 + g * 4 + rr;
            const float s = sacc[nt][rr] * scale;
            sv[nt][rr] = (key > qr) ? -1e30f : s;
          }
        // ---- row max via DPP ----
        float pm[4];
#pragma unroll
        for (int rr = 0; rr < 4; ++rr) pm[rr] = fmaxf(sv[0][rr], sv[1][rr]);
#pragma unroll
        for (int rr = 0; rr < 4; ++rr) {
          pm[rr] = fmaxf(pm[rr], DPPF(pm[rr], 0xB1));
          pm[rr] = fmaxf(pm[rr], DPPF(pm[rr], 0x4E));
          pm[rr] = fmaxf(pm[rr], DPPF(pm[rr], 0x141));
          pm[rr] = fmaxf(pm[rr], DPPF(pm[rr], 0x140));
        }
        // ---- defer-rescale (T13) ----
        bool ok = true;
#pragma unroll
        for (int rr = 0; rr < 4; ++rr) ok = ok && (pm[rr] <= mrow[rr] + 8.f);
        if (!__all((int)ok)) {
#pragma unroll
          for (int rr = 0; rr < 4; ++rr) {
            const float mnew = fmaxf(mrow[rr], pm[rr]);
            const float corr = __expf(mrow[rr] - mnew);
            mrow[rr] = mnew;
            lrow[rr] *= corr;
#pragma unroll
            for (int ht = 0; ht < 8; ++ht) oacc[ht][rr] *= corr;
          }
        }
        // ---- P = exp(S - m), wave-private LDS tile, row-sum via DPP ----
        float rs[4];
#pragma unroll
        for (int rr = 0; rr < 4; ++rr) {
          const float p0 = __expf(sv[0][rr] - mrow[rr]);
          const float p1 = __expf(sv[1][rr] - mrow[rr]);
          Pl[wave][g * 4 + rr][lr] = __float2bfloat16(p0);
          Pl[wave][g * 4 + rr][16 + lr] = __float2bfloat16(p1);
          rs[rr] = p0 + p1;
        }
#pragma unroll
        for (int rr = 0; rr < 4; ++rr) {
          rs[rr] += DPPF(rs[rr], 0xB1);
          rs[rr] += DPPF(rs[rr], 0x4E);
          rs[rr] += DPPF(rs[rr], 0x141);
          rs[rr] += DPPF(rs[rr], 0x140);
        }
#pragma unroll
        for (int rr = 0; rr < 4; ++rr) lrow[rr] += rs[rr];
        // ---- PV ----
        bf16x8 pf = *reinterpret_cast<const bf16x8*>(&Pl[wave][lr][g * 8]);
#pragma unroll
        for (int ht = 0; ht < 8; ++ht)
          oacc[ht] = __builtin_amdgcn_mfma_f32_16x16x32_bf16(pf, vf[ht],
                                                             oacc[ht], 0, 0, 0);
      }
      __syncthreads();
      __hip_bfloat16* t = bufA; bufA = bufB; bufB = t;
    }

    // ---- kp-pair merge ----
    if (kp == 1) {
#pragma unroll
      for (int ht = 0; ht < 8; ++ht)
#pragma unroll
        for (int rr = 0; rr < 4; ++rr)
          Obuf[qt][g * 4 + rr][ht * 16 + lr] = oacc[ht][rr];
      if (lr == 0) {
#pragma unroll
        for (int rr = 0; rr < 4; ++rr) {
          mbuf[wave][g * 4 + rr] = mrow[rr];
          lbuf[wave][g * 4 + rr] = lrow[rr];
        }
      }
    }
    __syncthreads();
    if (kp == 0) {
#pragma unroll
      for (int rr = 0; rr < 4; ++rr) {
        const float mB = mbuf[wave + 1][g * 4 + rr];
        const float lB = lbuf[wave + 1][g * 4 + rr];
        const float M = fmaxf(mrow[rr], mB);
        const float a = __expf(mrow[rr] - M);
        const float bt = __expf(mB - M);
        lrow[rr] = a * lrow[rr] + bt * lB;
        mrow[rr] = M;
#pragma unroll
        for (int ht = 0; ht < 8; ++ht)
          oacc[ht][rr] =
              a * oacc[ht][rr] + bt * Obuf[qt][g * 4 + rr][ht * 16 + lr];
      }
      if (mode == 0) {
#pragma unroll
        for (int ht = 0; ht < 8; ++ht)
#pragma unroll
          for (int rr = 0; rr < 4; ++rr) {
            const int qr = qrow0 + g * 4 + rr;
            out[((size_t)b * T_SEQ + qr) * H_DIM + ht * 16 + lr] =
                oacc[ht][rr] / lrow[rr];
          }
      } else {
        float* PO = (mode == 1) ? PA_O : PB_O;
        float* Pm = (mode == 1) ? PA_ml : PB_ml;
        const int slot = tile - 16;
#pragma unroll
        for (int rr = 0; rr < 4; ++rr) {
          const size_t pr = (size_t)(b * 16 + slot) * 64 + qt * 16 + g * 4 + rr;
#pragma unroll
          for (int ht = 0; ht < 8; ++ht)
            PO[pr * 128 + ht * 16 + lr] = oacc[ht][rr];
          if (lr == 0) {
            Pm[pr * 2 + 0] = mrow[rr];
            Pm[pr * 2 + 1] = lrow[rr];
          }
        }
      }
    }
    __syncthreads();
  };

  if (u < 16) {
    process(u, 0, u, 0);                 // light tile, full, direct out
    process(31 - u, 0, 15 - u, 1);       // heavy tile, early keys, partial A
  } else {
    const int v = u - 16;
    process(31 - v, 16 - v, 31 - v, 2);  // heavy tile, late keys, partial B
  }
}

// Merge the two partials of each heavy tile. grid = 8*16 = 128 blocks.
__global__ __launch_bounds__(256) void combine_kernel(
    const float* __restrict__ PA_O, const float* __restrict__ PA_ml,
    const float* __restrict__ PB_O, const float* __restrict__ PB_ml,
    float* __restrict__ out) {
  const int b = blockIdx.x >> 4;
  const int s = blockIdx.x & 15;
  const int tid = threadIdx.x;
  const int row = tid >> 2;          // 0..63
  const int c0 = (tid & 3) * 32;
  const size_t pr = (size_t)(b * 16 + s) * 64 + row;
  const float mA = PA_ml[pr * 2], lA = PA_ml[pr * 2 + 1];
  const float mB = PB_ml[pr * 2], lB = PB_ml[pr * 2 + 1];
  const float M = fmaxf(mA, mB);
  const float a = __expf(mA - M), bb = __expf(mB - M);
  const float inv = 1.f / (a * lA + bb * lB);
  const float* oa = PA_O + pr * 128 + c0;
  const float* ob = PB_O + pr * 128 + c0;
  float* op = out + ((size_t)b * T_SEQ + (16 + s) * 64 + row) * H_DIM + c0;
#pragma unroll
  for (int i = 0; i < 32; i += 4) {
    const float4 x = *reinterpret_cast<const float4*>(oa + i);
    const float4 y = *reinterpret_cast<const float4*>(ob + i);
    float4 z;
    z.x = (a * x.x + bb * y.x) * inv;
    z.y = (a * x.y + bb * y.y) * inv;
    z.z = (a * x.z + bb * y.z) * inv;
    z.w = (a * x.w + bb * y.w) * inv;
    *reinterpret_cast<float4*>(op + i) = z;
  }
}

extern "C" void kernel_launch(void* const* d_in, const int* in_sizes, int n_in,
                              void* d_out, int out_size, void* d_ws, size_t ws_size,
                              hipStream_t stream) {
  const float* x = (const float*)d_in[0];
  const float* Wq = (const float*)d_in[1];
  const float* Wk = (const float*)d_in[2];
  const float* Wv = (const float*)d_in[3];
  float* out = (float*)d_out;

  __hip_bfloat16* Wt = (__hip_bfloat16*)d_ws;
  __hip_bfloat16* qbuf = Wt + (size_t)3 * 128 * 1024;
  __hip_bfloat16* kbuf = qbuf + (size_t)NTOK * H_DIM;
  __hip_bfloat16* vbuf = kbuf + (size_t)NTOK * H_DIM;
  float* fbase = (float*)(vbuf + (size_t)NBATCH * H_DIM * T_SEQ);
  float* PA_O = fbase;                       // 8*16*64*128 = 1,048,576 f
  float* PA_ml = PA_O + (size_t)1048576;     // 16,384 f
  float* PB_O = PA_ml + 16384;
  float* PB_ml = PB_O + (size_t)1048576;

  hipLaunchKernelGGL(prep_w_kernel, dim3(384), dim3(256), 0, stream, Wq, Wk, Wv, Wt);
  hipLaunchKernelGGL(proj_kernel, dim3(256), dim3(512), 0, stream, x, Wt, qbuf,
                     kbuf, vbuf);
  hipLaunchKernelGGL(attn_kernel, dim3(256), dim3(512), 0, stream, qbuf, kbuf,
                     vbuf, out, PA_O, PA_ml, PB_O, PB_ml);
  hipLaunchKernelGGL(combine_kernel, dim3(128), dim3(256), 0, stream, PA_O,
                     PA_ml, PB_O, PB_ml, out);
}

// Round 9
// 71.244 us; speedup vs baseline: 1.7875x; 1.0052x over previous
//
#include <hip/hip_runtime.h>
#include <hip/hip_bf16.h>
#include <stdint.h>

typedef float f32x4 __attribute__((ext_vector_type(4)));
typedef __bf16 bf16x8 __attribute__((ext_vector_type(8)));

#define T_SEQ 2048
#define D_EMB 1024
#define H_DIM 128
#define NBATCH 8
#define NTOK 16384  // NBATCH * T_SEQ

typedef __attribute__((address_space(3))) uint32_t lds_u32;
typedef const __attribute__((address_space(1))) uint32_t glb_u32;

// DPP cross-lane (within 16-lane row): VALU-latency replacement for shfl_xor
#define DPPF(x, ctrl)                                                    \
  __int_as_float(__builtin_amdgcn_update_dpp(                            \
      0, __float_as_int(x), (ctrl), 0xF, 0xF, true))

// ---------------------------------------------------------------------------
// ws layout:
//   bf16: Wt[3][128][1024] | qb[16384][128] | kb[16384][128] | vt[8][128][2048]
//   f32 : PA_O[8][16][64][128] PA_ml[8][16][64][2] PB_O[...] PB_ml[...]
// ---------------------------------------------------------------------------

__global__ __launch_bounds__(256) void prep_w_kernel(
    const float* __restrict__ Wq, const float* __restrict__ Wk,
    const float* __restrict__ Wv, __hip_bfloat16* __restrict__ Wt) {
  const int mat = blockIdx.x >> 7;   // 0..2
  const int h = blockIdx.x & 127;
  const float* W = (mat == 0) ? Wq : ((mat == 1) ? Wk : Wv);
  __hip_bfloat16* dst = Wt + (size_t)(mat * 128 + h) * D_EMB;
  for (int k = threadIdx.x; k < D_EMB; k += 256)
    dst[k] = __float2bfloat16(W[(size_t)k * H_DIM + h]);
}

// Projection GEMM: C[16384,384] = x * Wt^T, BM=64 BN=384(full) BK=64.
// Fully async staging: BOTH A (fp32 x, 16 KB/step from HBM) and B (bf16 Wt,
// 48 KB/step from L2) go through global_load_lds with pre-swizzled global
// sources + linear LDS dests (rule 21); fp32->bf16 conversion happens at
// fragment-read time (compiler emits v_cvt_pk_bf16_f32). One barrier/step
// drains staging issued a full compute-phase earlier.
__global__ __launch_bounds__(512) void proj_kernel(
    const float* __restrict__ x, const __hip_bfloat16* __restrict__ Wt,
    __hip_bfloat16* __restrict__ qb, __hip_bfloat16* __restrict__ kb,
    __hip_bfloat16* __restrict__ vt) {
  __shared__ __align__(16) float Af[2][64 * 64];            // 2 x 16 KB fp32
  __shared__ __align__(16) __hip_bfloat16 Bs[2][384 * 64];  // 2 x 48 KB
  const int tid = threadIdx.x;
  const int wave = tid >> 6;
  const int lane = tid & 63;
  const int g = lane >> 4;
  const int lr = lane & 15;
  const int m0 = blockIdx.x * 64;
  const int wc = wave * 48;   // 48 % 8 == 0 -> (wc+n*16+lr)&7 == lr&7

  f32x4 acc[4][3];
#pragma unroll
  for (int m = 0; m < 4; ++m)
#pragma unroll
    for (int n = 0; n < 3; ++n) acc[m][n] = f32x4{0.f, 0.f, 0.f, 0.f};

  // A: 64 rows x 16 units (16B = 4 floats). LDS slot s holds logical unit
  // s ^ (row&15)  (involution; read applies the same XOR).
  auto stageA = [&](int buf, int k0) {
#pragma unroll
    for (int i = 0; i < 2; ++i) {
      const int e = i * 512 + tid;      // 0..1023
      const int row = e >> 4;           // 0..63
      const int un = e & 15;
      __builtin_amdgcn_global_load_lds(
          (glb_u32*)(uintptr_t)(x + (size_t)(m0 + row) * D_EMB + k0 +
                                ((un ^ (row & 15)) * 4)),
          (lds_u32*)(uintptr_t)(&Af[buf][e * 4]), 16, 0, 0);
    }
  };
  // B: 384 rows x 8 chunks (16B = 8 bf16), chunk swizzled by row&7.
  auto stageB = [&](int buf, int k0) {
#pragma unroll
    for (int i = 0; i < 6; ++i) {
      const int u = i * 512 + tid;   // 0..3071
      const int row = u >> 3;        // 0..383
      const int chunk = u & 7;
      __builtin_amdgcn_global_load_lds(
          (glb_u32*)(uintptr_t)(Wt + (size_t)row * D_EMB + k0 +
                                ((chunk ^ (row & 7)) * 8)),
          (lds_u32*)(uintptr_t)(&Bs[buf][row * 64 + chunk * 8]), 16, 0, 0);
    }
  };
  auto compute = [&](int buf) {
#pragma unroll
    for (int kk = 0; kk < 2; ++kk) {
      bf16x8 a[4];
#pragma unroll
      for (int m = 0; m < 4; ++m) {
        const int row = m * 16 + lr;
        const int u0 = kk * 8 + g * 2;
        const f32x4 lo = *reinterpret_cast<const f32x4*>(
            &Af[buf][row * 64 + ((u0 ^ (row & 15)) * 4)]);
        const f32x4 hi = *reinterpret_cast<const f32x4*>(
            &Af[buf][row * 64 + (((u0 + 1) ^ (row & 15)) * 4)]);
        union { bf16x8 v; __hip_bfloat16 h[8]; } u;
        u.h[0] = __float2bfloat16(lo[0]);
        u.h[1] = __float2bfloat16(lo[1]);
        u.h[2] = __float2bfloat16(lo[2]);
        u.h[3] = __float2bfloat16(lo[3]);
        u.h[4] = __float2bfloat16(hi[0]);
        u.h[5] = __float2bfloat16(hi[1]);
        u.h[6] = __float2bfloat16(hi[2]);
        u.h[7] = __float2bfloat16(hi[3]);
        a[m] = u.v;
      }
#pragma unroll
      for (int n = 0; n < 3; ++n) {
        const int row = wc + n * 16 + lr;
        bf16x8 b = *reinterpret_cast<const bf16x8*>(
            &Bs[buf][row * 64 + (((kk * 4 + g) ^ (row & 7)) * 8)]);
#pragma unroll
        for (int m = 0; m < 4; ++m)
          acc[m][n] =
              __builtin_amdgcn_mfma_f32_16x16x32_bf16(a[m], b, acc[m][n], 0, 0, 0);
      }
    }
  };

  // ---- prologue ----
  stageA(0, 0);
  stageB(0, 0);
  __syncthreads();

  int cur = 0;
  for (int k = 0; k < 16; ++k) {
    if (k < 15) {                     // issue next step's staging first
      stageA(cur ^ 1, (k + 1) * 64);
      stageB(cur ^ 1, (k + 1) * 64);
    }
    compute(cur);                     // MFMA + cvt hide the transfer
    __syncthreads();                  // single drain point per step
    cur ^= 1;
  }

  // ---- store: C layout col=lane&15, row=(lane>>4)*4+reg ----
#pragma unroll
  for (int n = 0; n < 3; ++n) {
    const int ng = wc + n * 16 + lr;  // 0..383
    const int head = ng >> 7;         // 0:q 1:k 2:v
    const int h = ng & 127;
#pragma unroll
    for (int m = 0; m < 4; ++m) {
#pragma unroll
      for (int r = 0; r < 4; ++r) {
        const int row = m0 + m * 16 + g * 4 + r;  // global token
        const __hip_bfloat16 val = __float2bfloat16(acc[m][n][r]);
        if (head == 0) {
          qb[(size_t)row * H_DIM + h] = val;
        } else if (head == 1) {
          kb[(size_t)row * H_DIM + h] = val;
        } else {
          const int bi = row >> 11;
          const int t = row & (T_SEQ - 1);
          vt[((size_t)bi * H_DIM + h) * T_SEQ + t] = val;
        }
      }
    }
  }
}

// Flash attention, LDS-shared K/V + causal pairing + DPP softmax reductions.
// (unchanged from R7/R8)
__global__ __launch_bounds__(512) void attn_kernel(
    const __hip_bfloat16* __restrict__ qb, const __hip_bfloat16* __restrict__ kb,
    const __hip_bfloat16* __restrict__ vt, float* __restrict__ out,
    float* __restrict__ PA_O, float* __restrict__ PA_ml,
    float* __restrict__ PB_O, float* __restrict__ PB_ml) {
  __shared__ __align__(16) __hip_bfloat16 KV[2][16384];   // 64 KB
  __shared__ __align__(16) __hip_bfloat16 Pl[8][16][40];  // 10 KB
  __shared__ float Obuf[4][16][132];                      // 33.8 KB
  __shared__ float mbuf[8][16];
  __shared__ float lbuf[8][16];

  const int tid = threadIdx.x;
  const int wave = tid >> 6;
  const int lane = tid & 63;
  const int g = lane >> 4;
  const int lr = lane & 15;
  const int qt = wave >> 1;   // q-subtile 0..3
  const int kp = wave & 1;    // key partition 0..1
  const int idx = blockIdx.x;
  const int b = idx & 7;
  const int u = idx >> 3;     // 0..31

  const __hip_bfloat16* qB = qb + (size_t)b * T_SEQ * H_DIM;
  const __hip_bfloat16* kB = kb + (size_t)b * T_SEQ * H_DIM;
  const __hip_bfloat16* vB = vt + (size_t)b * H_DIM * T_SEQ;
  const float scale = 0.08838834764831845f;  // 1/sqrt(128)

  auto stage = [&](__hip_bfloat16* buf, int s0) {
#pragma unroll
    for (int i = 0; i < 2; ++i) {
      const int uu = tid + i * 512;
      const int row = uu >> 4, grp = uu & 15;
      __builtin_amdgcn_global_load_lds(
          (glb_u32*)(uintptr_t)(kB + (size_t)(s0 + row) * H_DIM +
                                ((grp ^ (row & 15)) * 8)),
          (lds_u32*)(uintptr_t)(buf + uu * 8), 16, 0, 0);
    }
#pragma unroll
    for (int i = 0; i < 2; ++i) {
      const int uu = tid + i * 512;
      const int h = uu >> 3, grp = uu & 7;
      __builtin_amdgcn_global_load_lds(
          (glb_u32*)(uintptr_t)(vB + (size_t)h * T_SEQ + s0 +
                                ((grp ^ (h & 7)) * 8)),
          (lds_u32*)(uintptr_t)(buf + 8192 + uu * 8), 16, 0, 0);
    }
  };

  // mode: 0 = direct out, 1 = partial A, 2 = partial B
  auto process = [&](int tile, int rr0, int rr1, int mode) {
    const int qrow0 = tile * 64 + qt * 16;
    bf16x8 qf[4];
#pragma unroll
    for (int kt = 0; kt < 4; ++kt)
      qf[kt] = *reinterpret_cast<const bf16x8*>(
          qB + (size_t)(qrow0 + lr) * H_DIM + kt * 32 + g * 8);

    f32x4 oacc[8];
#pragma unroll
    for (int i = 0; i < 8; ++i) oacc[i] = f32x4{0.f, 0.f, 0.f, 0.f};
    float mrow[4] = {-1e30f, -1e30f, -1e30f, -1e30f};
    float lrow[4] = {0.f, 0.f, 0.f, 0.f};

    __hip_bfloat16* bufA = &KV[0][0];
    __hip_bfloat16* bufB = &KV[1][0];
    stage(bufA, rr0 * 64);
    __syncthreads();

    for (int r = rr0; r <= rr1; ++r) {
      if (r < rr1) stage(bufB, (r + 1) * 64);
      const int s0 = r * 64;
      const bool active = (s0 + kp * 32) <= (qrow0 + 15);
      if (active) {
        // ---- QK^T from swizzled K tile ----
        f32x4 sacc[2];
        sacc[0] = f32x4{0.f, 0.f, 0.f, 0.f};
        sacc[1] = f32x4{0.f, 0.f, 0.f, 0.f};
#pragma unroll
        for (int nt = 0; nt < 2; ++nt) {
          const int kl = kp * 32 + nt * 16 + lr;
          const __hip_bfloat16* kr = bufA + kl * 128;
#pragma unroll
          for (int kt = 0; kt < 4; ++kt) {
            bf16x8 kf = *reinterpret_cast<const bf16x8*>(
                kr + (((kt * 4 + g) ^ (kl & 15)) * 8));
            sacc[nt] = __builtin_amdgcn_mfma_f32_16x16x32_bf16(qf[kt], kf,
                                                               sacc[nt], 0, 0, 0);
          }
        }
        // ---- V fragments early (LDS latency hides under softmax) ----
        bf16x8 vf[8];
#pragma unroll
        for (int ht = 0; ht < 8; ++ht) {
          const int h = ht * 16 + lr;
          vf[ht] = *reinterpret_cast<const bf16x8*>(
              bufA + 8192 + h * 64 + (((kp * 4 + g) ^ (h & 7)) * 8));
        }
        // ---- scale + causal mask ----
        float sv[2][4];
#pragma unroll
        for (int nt = 0; nt < 2; ++nt)
#pragma unroll
          for (int rr = 0; rr < 4; ++rr) {
            const int key = s0 + kp * 32 + nt * 16 + lr;
            const int qr = qrow0 + g * 4 + rr;
            const float s = sacc[nt][rr] * scale;
            sv[nt][rr] = (key > qr) ? -1e30f : s;
          }
        // ---- row max via DPP ----
        float pm[4];
#pragma unroll
        for (int rr = 0; rr < 4; ++rr) pm[rr] = fmaxf(sv[0][rr], sv[1][rr]);
#pragma unroll
        for (int rr = 0; rr < 4; ++rr) {
          pm[rr] = fmaxf(pm[rr], DPPF(pm[rr], 0xB1));
          pm[rr] = fmaxf(pm[rr], DPPF(pm[rr], 0x4E));
          pm[rr] = fmaxf(pm[rr], DPPF(pm[rr], 0x141));
          pm[rr] = fmaxf(pm[rr], DPPF(pm[rr], 0x140));
        }
        // ---- defer-rescale (T13) ----
        bool ok = true;
#pragma unroll
        for (int rr = 0; rr < 4; ++rr) ok = ok && (pm[rr] <= mrow[rr] + 8.f);
        if (!__all((int)ok)) {
#pragma unroll
          for (int rr = 0; rr < 4; ++rr) {
            const float mnew = fmaxf(mrow[rr], pm[rr]);
            const float corr = __expf(mrow[rr] - mnew);
            mrow[rr] = mnew;
            lrow[rr] *= corr;
#pragma unroll
            for (int ht = 0; ht < 8; ++ht) oacc[ht][rr] *= corr;
          }
        }
        // ---- P = exp(S - m), wave-private LDS tile, row-sum via DPP ----
        float rs[4];
#pragma unroll
        for (int rr = 0; rr < 4; ++rr) {
          const float p0 = __expf(sv[0][rr] - mrow[rr]);
          const float p1 = __expf(sv[1][rr] - mrow[rr]);
          Pl[wave][g * 4 + rr][lr] = __float2bfloat16(p0);
          Pl[wave][g * 4 + rr][16 + lr] = __float2bfloat16(p1);
          rs[rr] = p0 + p1;
        }
#pragma unroll
        for (int rr = 0; rr < 4; ++rr) {
          rs[rr] += DPPF(rs[rr], 0xB1);
          rs[rr] += DPPF(rs[rr], 0x4E);
          rs[rr] += DPPF(rs[rr], 0x141);
          rs[rr] += DPPF(rs[rr], 0x140);
        }
#pragma unroll
        for (int rr = 0; rr < 4; ++rr) lrow[rr] += rs[rr];
        // ---- PV ----
        bf16x8 pf = *reinterpret_cast<const bf16x8*>(&Pl[wave][lr][g * 8]);
#pragma unroll
        for (int ht = 0; ht < 8; ++ht)
          oacc[ht] = __builtin_amdgcn_mfma_f32_16x16x32_bf16(pf, vf[ht],
                                                             oacc[ht], 0, 0, 0);
      }
      __syncthreads();
      __hip_bfloat16* t = bufA; bufA = bufB; bufB = t;
    }

    // ---- kp-pair merge ----
    if (kp == 1) {
#pragma unroll
      for (int ht = 0; ht < 8; ++ht)
#pragma unroll
        for (int rr = 0; rr < 4; ++rr)
          Obuf[qt][g * 4 + rr][ht * 16 + lr] = oacc[ht][rr];
      if (lr == 0) {
#pragma unroll
        for (int rr = 0; rr < 4; ++rr) {
          mbuf[wave][g * 4 + rr] = mrow[rr];
          lbuf[wave][g * 4 + rr] = lrow[rr];
        }
      }
    }
    __syncthreads();
    if (kp == 0) {
#pragma unroll
      for (int rr = 0; rr < 4; ++rr) {
        const float mB = mbuf[wave + 1][g * 4 + rr];
        const float lB = lbuf[wave + 1][g * 4 + rr];
        const float M = fmaxf(mrow[rr], mB);
        const float a = __expf(mrow[rr] - M);
        const float bt = __expf(mB - M);
        lrow[rr] = a * lrow[rr] + bt * lB;
        mrow[rr] = M;
#pragma unroll
        for (int ht = 0; ht < 8; ++ht)
          oacc[ht][rr] =
              a * oacc[ht][rr] + bt * Obuf[qt][g * 4 + rr][ht * 16 + lr];
      }
      if (mode == 0) {
#pragma unroll
        for (int ht = 0; ht < 8; ++ht)
#pragma unroll
          for (int rr = 0; rr < 4; ++rr) {
            const int qr = qrow0 + g * 4 + rr;
            out[((size_t)b * T_SEQ + qr) * H_DIM + ht * 16 + lr] =
                oacc[ht][rr] / lrow[rr];
          }
      } else {
        float* PO = (mode == 1) ? PA_O : PB_O;
        float* Pm = (mode == 1) ? PA_ml : PB_ml;
        const int slot = tile - 16;
#pragma unroll
        for (int rr = 0; rr < 4; ++rr) {
          const size_t pr = (size_t)(b * 16 + slot) * 64 + qt * 16 + g * 4 + rr;
#pragma unroll
          for (int ht = 0; ht < 8; ++ht)
            PO[pr * 128 + ht * 16 + lr] = oacc[ht][rr];
          if (lr == 0) {
            Pm[pr * 2 + 0] = mrow[rr];
            Pm[pr * 2 + 1] = lrow[rr];
          }
        }
      }
    }
    __syncthreads();
  };

  if (u < 16) {
    process(u, 0, u, 0);                 // light tile, full, direct out
    process(31 - u, 0, 15 - u, 1);       // heavy tile, early keys, partial A
  } else {
    const int v = u - 16;
    process(31 - v, 16 - v, 31 - v, 2);  // heavy tile, late keys, partial B
  }
}

// Merge the two partials of each heavy tile. grid = 8*16 = 128 blocks.
__global__ __launch_bounds__(256) void combine_kernel(
    const float* __restrict__ PA_O, const float* __restrict__ PA_ml,
    const float* __restrict__ PB_O, const float* __restrict__ PB_ml,
    float* __restrict__ out) {
  const int b = blockIdx.x >> 4;
  const int s = blockIdx.x & 15;
  const int tid = threadIdx.x;
  const int row = tid >> 2;          // 0..63
  const int c0 = (tid & 3) * 32;
  const size_t pr = (size_t)(b * 16 + s) * 64 + row;
  const float mA = PA_ml[pr * 2], lA = PA_ml[pr * 2 + 1];
  const float mB = PB_ml[pr * 2], lB = PB_ml[pr * 2 + 1];
  const float M = fmaxf(mA, mB);
  const float a = __expf(mA - M), bb = __expf(mB - M);
  const float inv = 1.f / (a * lA + bb * lB);
  const float* oa = PA_O + pr * 128 + c0;
  const float* ob = PB_O + pr * 128 + c0;
  float* op = out + ((size_t)b * T_SEQ + (16 + s) * 64 + row) * H_DIM + c0;
#pragma unroll
  for (int i = 0; i < 32; i += 4) {
    const float4 x = *reinterpret_cast<const float4*>(oa + i);
    const float4 y = *reinterpret_cast<const float4*>(ob + i);
    float4 z;
    z.x = (a * x.x + bb * y.x) * inv;
    z.y = (a * x.y + bb * y.y) * inv;
    z.z = (a * x.z + bb * y.z) * inv;
    z.w = (a * x.w + bb * y.w) * inv;
    *reinterpret_cast<float4*>(op + i) = z;
  }
}

extern "C" void kernel_launch(void* const* d_in, const int* in_sizes, int n_in,
                              void* d_out, int out_size, void* d_ws, size_t ws_size,
                              hipStream_t stream) {
  const float* x = (const float*)d_in[0];
  const float* Wq = (const float*)d_in[1];
  const float* Wk = (const float*)d_in[2];
  const float* Wv = (const float*)d_in[3];
  float* out = (float*)d_out;

  __hip_bfloat16* Wt = (__hip_bfloat16*)d_ws;
  __hip_bfloat16* qbuf = Wt + (size_t)3 * 128 * 1024;
  __hip_bfloat16* kbuf = qbuf + (size_t)NTOK * H_DIM;
  __hip_bfloat16* vbuf = kbuf + (size_t)NTOK * H_DIM;
  float* fbase = (float*)(vbuf + (size_t)NBATCH * H_DIM * T_SEQ);
  float* PA_O = fbase;                       // 8*16*64*128 = 1,048,576 f
  float* PA_ml = PA_O + (size_t)1048576;     // 16,384 f
  float* PB_O = PA_ml + 16384;
  float* PB_ml = PB_O + (size_t)1048576;

  hipLaunchKernelGGL(prep_w_kernel, dim3(384), dim3(256), 0, stream, Wq, Wk, Wv, Wt);
  hipLaunchKernelGGL(proj_kernel, dim3(256), dim3(512), 0, stream, x, Wt, qbuf,
                     kbuf, vbuf);
  hipLaunchKernelGGL(attn_kernel, dim3(256), dim3(512), 0, stream, qbuf, kbuf,
                     vbuf, out, PA_O, PA_ml, PB_O, PB_ml);
  hipLaunchKernelGGL(combine_kernel, dim3(128), dim3(256), 0, stream, PA_O,
                     PA_ml, PB_O, PB_ml, out);
}

// Round 10
// 70.630 us; speedup vs baseline: 1.8030x; 1.0087x over previous
//
#include <hip/hip_runtime.h>
#include <hip/hip_bf16.h>
#include <stdint.h>

typedef float f32x4 __attribute__((ext_vector_type(4)));
typedef __bf16 bf16x8 __attribute__((ext_vector_type(8)));

#define T_SEQ 2048
#define D_EMB 1024
#define H_DIM 128
#define NBATCH 8
#define NTOK 16384  // NBATCH * T_SEQ

typedef __attribute__((address_space(3))) uint32_t lds_u32;
typedef const __attribute__((address_space(1))) uint32_t glb_u32;

// DPP cross-lane (within 16-lane row): VALU-latency replacement for shfl_xor
#define DPPF(x, ctrl)                                                    \
  __int_as_float(__builtin_amdgcn_update_dpp(                            \
      0, __float_as_int(x), (ctrl), 0xF, 0xF, true))

// Pipeline fence: wait for ALL outstanding global_load_lds (issued one full
// compute-phase ago), then join waves. sched_barrier pins ds_reads below.
#define PIPE_FENCE()                                       \
  do {                                                     \
    asm volatile("s_waitcnt vmcnt(0)" ::: "memory");       \
    __builtin_amdgcn_s_barrier();                          \
    __builtin_amdgcn_sched_barrier(0);                     \
  } while (0)

// ---------------------------------------------------------------------------
// ws layout:
//   bf16: Wt[3][128][1024] | qb[16384][128] | kb[16384][128] | vt[8][128][2048]
//   f32 : PA_O[8][16][64][128] PA_ml[8][16][64][2] PB_O[...] PB_ml[...]
// ---------------------------------------------------------------------------

__global__ __launch_bounds__(256) void prep_w_kernel(
    const float* __restrict__ Wq, const float* __restrict__ Wk,
    const float* __restrict__ Wv, __hip_bfloat16* __restrict__ Wt) {
  const int mat = blockIdx.x >> 7;   // 0..2
  const int h = blockIdx.x & 127;
  const float* W = (mat == 0) ? Wq : ((mat == 1) ? Wk : Wv);
  __hip_bfloat16* dst = Wt + (size_t)(mat * 128 + h) * D_EMB;
  for (int k = threadIdx.x; k < D_EMB; k += 256)
    dst[k] = __float2bfloat16(W[(size_t)k * H_DIM + h]);
}

// Projection GEMM: C[16384,384] = x * Wt^T, BM=64 BN=384(full) BK=64.
// Async staging (gload_lds, pre-swizzled sources, linear LDS) + software
// pipeline with the drain moved BEFORE the overlap window:
//   step k: { vmcnt(0)+barrier  [drains stage(k), issued a full step ago];
//             issue stage(k+1); compute(k) }
__global__ __launch_bounds__(512) void proj_kernel(
    const float* __restrict__ x, const __hip_bfloat16* __restrict__ Wt,
    __hip_bfloat16* __restrict__ qb, __hip_bfloat16* __restrict__ kb,
    __hip_bfloat16* __restrict__ vt) {
  __shared__ __align__(16) float Af[2][64 * 64];            // 2 x 16 KB fp32
  __shared__ __align__(16) __hip_bfloat16 Bs[2][384 * 64];  // 2 x 48 KB
  const int tid = threadIdx.x;
  const int wave = tid >> 6;
  const int lane = tid & 63;
  const int g = lane >> 4;
  const int lr = lane & 15;
  const int m0 = blockIdx.x * 64;
  const int wc = wave * 48;   // 48 % 8 == 0 -> (wc+n*16+lr)&7 == lr&7

  f32x4 acc[4][3];
#pragma unroll
  for (int m = 0; m < 4; ++m)
#pragma unroll
    for (int n = 0; n < 3; ++n) acc[m][n] = f32x4{0.f, 0.f, 0.f, 0.f};

  // A: 64 rows x 16 units (16B = 4 floats). LDS slot s holds logical unit
  // s ^ (row&15)  (involution; read applies the same XOR).
  auto stageA = [&](int buf, int k0) {
#pragma unroll
    for (int i = 0; i < 2; ++i) {
      const int e = i * 512 + tid;      // 0..1023
      const int row = e >> 4;           // 0..63
      const int un = e & 15;
      __builtin_amdgcn_global_load_lds(
          (glb_u32*)(uintptr_t)(x + (size_t)(m0 + row) * D_EMB + k0 +
                                ((un ^ (row & 15)) * 4)),
          (lds_u32*)(uintptr_t)(&Af[buf][e * 4]), 16, 0, 0);
    }
  };
  // B: 384 rows x 8 chunks (16B = 8 bf16), chunk swizzled by row&7.
  auto stageB = [&](int buf, int k0) {
#pragma unroll
    for (int i = 0; i < 6; ++i) {
      const int u = i * 512 + tid;   // 0..3071
      const int row = u >> 3;        // 0..383
      const int chunk = u & 7;
      __builtin_amdgcn_global_load_lds(
          (glb_u32*)(uintptr_t)(Wt + (size_t)row * D_EMB + k0 +
                                ((chunk ^ (row & 7)) * 8)),
          (lds_u32*)(uintptr_t)(&Bs[buf][row * 64 + chunk * 8]), 16, 0, 0);
    }
  };
  auto compute = [&](int buf) {
#pragma unroll
    for (int kk = 0; kk < 2; ++kk) {
      bf16x8 a[4];
#pragma unroll
      for (int m = 0; m < 4; ++m) {
        const int row = m * 16 + lr;
        const int u0 = kk * 8 + g * 2;
        const f32x4 lo = *reinterpret_cast<const f32x4*>(
            &Af[buf][row * 64 + ((u0 ^ (row & 15)) * 4)]);
        const f32x4 hi = *reinterpret_cast<const f32x4*>(
            &Af[buf][row * 64 + (((u0 + 1) ^ (row & 15)) * 4)]);
        union { bf16x8 v; __hip_bfloat16 h[8]; } u;
        u.h[0] = __float2bfloat16(lo[0]);
        u.h[1] = __float2bfloat16(lo[1]);
        u.h[2] = __float2bfloat16(lo[2]);
        u.h[3] = __float2bfloat16(lo[3]);
        u.h[4] = __float2bfloat16(hi[0]);
        u.h[5] = __float2bfloat16(hi[1]);
        u.h[6] = __float2bfloat16(hi[2]);
        u.h[7] = __float2bfloat16(hi[3]);
        a[m] = u.v;
      }
#pragma unroll
      for (int n = 0; n < 3; ++n) {
        const int row = wc + n * 16 + lr;
        bf16x8 b = *reinterpret_cast<const bf16x8*>(
            &Bs[buf][row * 64 + (((kk * 4 + g) ^ (row & 7)) * 8)]);
#pragma unroll
        for (int m = 0; m < 4; ++m)
          acc[m][n] =
              __builtin_amdgcn_mfma_f32_16x16x32_bf16(a[m], b, acc[m][n], 0, 0, 0);
      }
    }
  };

  // ---- prologue: issue stage(0); first fence drains it ----
  stageA(0, 0);
  stageB(0, 0);

  int cur = 0;
  for (int k = 0; k < 16; ++k) {
    PIPE_FENCE();                     // drains stage(k) (one full step old)
    if (k < 15) {                     // issue stage(k+1); flies under compute
      stageA(cur ^ 1, (k + 1) * 64);
      stageB(cur ^ 1, (k + 1) * 64);
    }
    compute(cur);
    cur ^= 1;
  }

  // ---- store: C layout col=lane&15, row=(lane>>4)*4+reg ----
#pragma unroll
  for (int n = 0; n < 3; ++n) {
    const int ng = wc + n * 16 + lr;  // 0..383
    const int head = ng >> 7;         // 0:q 1:k 2:v
    const int h = ng & 127;
#pragma unroll
    for (int m = 0; m < 4; ++m) {
#pragma unroll
      for (int r = 0; r < 4; ++r) {
        const int row = m0 + m * 16 + g * 4 + r;  // global token
        const __hip_bfloat16 val = __float2bfloat16(acc[m][n][r]);
        if (head == 0) {
          qb[(size_t)row * H_DIM + h] = val;
        } else if (head == 1) {
          kb[(size_t)row * H_DIM + h] = val;
        } else {
          const int bi = row >> 11;
          const int t = row & (T_SEQ - 1);
          vt[((size_t)bi * H_DIM + h) * T_SEQ + t] = val;
        }
      }
    }
  }
}

// Flash attention, LDS-shared K/V + causal pairing + DPP softmax, now with
// the same drain-before-overlap pipeline as proj.
__global__ __launch_bounds__(512) void attn_kernel(
    const __hip_bfloat16* __restrict__ qb, const __hip_bfloat16* __restrict__ kb,
    const __hip_bfloat16* __restrict__ vt, float* __restrict__ out,
    float* __restrict__ PA_O, float* __restrict__ PA_ml,
    float* __restrict__ PB_O, float* __restrict__ PB_ml) {
  __shared__ __align__(16) __hip_bfloat16 KV[2][16384];   // 64 KB
  __shared__ __align__(16) __hip_bfloat16 Pl[8][16][40];  // 10 KB
  __shared__ float Obuf[4][16][132];                      // 33.8 KB
  __shared__ float mbuf[8][16];
  __shared__ float lbuf[8][16];

  const int tid = threadIdx.x;
  const int wave = tid >> 6;
  const int lane = tid & 63;
  const int g = lane >> 4;
  const int lr = lane & 15;
  const int qt = wave >> 1;   // q-subtile 0..3
  const int kp = wave & 1;    // key partition 0..1
  const int idx = blockIdx.x;
  const int b = idx & 7;
  const int u = idx >> 3;     // 0..31

  const __hip_bfloat16* qB = qb + (size_t)b * T_SEQ * H_DIM;
  const __hip_bfloat16* kB = kb + (size_t)b * T_SEQ * H_DIM;
  const __hip_bfloat16* vB = vt + (size_t)b * H_DIM * T_SEQ;
  const float scale = 0.08838834764831845f;  // 1/sqrt(128)

  auto stage = [&](__hip_bfloat16* buf, int s0) {
#pragma unroll
    for (int i = 0; i < 2; ++i) {
      const int uu = tid + i * 512;
      const int row = uu >> 4, grp = uu & 15;
      __builtin_amdgcn_global_load_lds(
          (glb_u32*)(uintptr_t)(kB + (size_t)(s0 + row) * H_DIM +
                                ((grp ^ (row & 15)) * 8)),
          (lds_u32*)(uintptr_t)(buf + uu * 8), 16, 0, 0);
    }
#pragma unroll
    for (int i = 0; i < 2; ++i) {
      const int uu = tid + i * 512;
      const int h = uu >> 3, grp = uu & 7;
      __builtin_amdgcn_global_load_lds(
          (glb_u32*)(uintptr_t)(vB + (size_t)h * T_SEQ + s0 +
                                ((grp ^ (h & 7)) * 8)),
          (lds_u32*)(uintptr_t)(buf + 8192 + uu * 8), 16, 0, 0);
    }
  };

  // mode: 0 = direct out, 1 = partial A, 2 = partial B
  auto process = [&](int tile, int rr0, int rr1, int mode) {
    const int qrow0 = tile * 64 + qt * 16;
    bf16x8 qf[4];
#pragma unroll
    for (int kt = 0; kt < 4; ++kt)
      qf[kt] = *reinterpret_cast<const bf16x8*>(
          qB + (size_t)(qrow0 + lr) * H_DIM + kt * 32 + g * 8);

    f32x4 oacc[8];
#pragma unroll
    for (int i = 0; i < 8; ++i) oacc[i] = f32x4{0.f, 0.f, 0.f, 0.f};
    float mrow[4] = {-1e30f, -1e30f, -1e30f, -1e30f};
    float lrow[4] = {0.f, 0.f, 0.f, 0.f};

    __hip_bfloat16* bufA = &KV[0][0];
    __hip_bfloat16* bufB = &KV[1][0];
    stage(bufA, rr0 * 64);   // drained by first PIPE_FENCE in loop

    for (int r = rr0; r <= rr1; ++r) {
      PIPE_FENCE();                          // drains stage(r) (one round old)
      if (r < rr1) stage(bufB, (r + 1) * 64);  // flies under compute(r)
      const int s0 = r * 64;
      const bool active = (s0 + kp * 32) <= (qrow0 + 15);
      if (active) {
        // ---- QK^T from swizzled K tile ----
        f32x4 sacc[2];
        sacc[0] = f32x4{0.f, 0.f, 0.f, 0.f};
        sacc[1] = f32x4{0.f, 0.f, 0.f, 0.f};
#pragma unroll
        for (int nt = 0; nt < 2; ++nt) {
          const int kl = kp * 32 + nt * 16 + lr;
          const __hip_bfloat16* kr = bufA + kl * 128;
#pragma unroll
          for (int kt = 0; kt < 4; ++kt) {
            bf16x8 kf = *reinterpret_cast<const bf16x8*>(
                kr + (((kt * 4 + g) ^ (kl & 15)) * 8));
            sacc[nt] = __builtin_amdgcn_mfma_f32_16x16x32_bf16(qf[kt], kf,
                                                               sacc[nt], 0, 0, 0);
          }
        }
        // ---- V fragments early (LDS latency hides under softmax) ----
        bf16x8 vf[8];
#pragma unroll
        for (int ht = 0; ht < 8; ++ht) {
          const int h = ht * 16 + lr;
          vf[ht] = *reinterpret_cast<const bf16x8*>(
              bufA + 8192 + h * 64 + (((kp * 4 + g) ^ (h & 7)) * 8));
        }
        // ---- scale + causal mask ----
        float sv[2][4];
#pragma unroll
        for (int nt = 0; nt < 2; ++nt)
#pragma unroll
          for (int rr = 0; rr < 4; ++rr) {
            const int key = s0 + kp * 32 + nt * 16 + lr;
            const int qr = qrow0 + g * 4 + rr;
            const float s = sacc[nt][rr] * scale;
            sv[nt][rr] = (key > qr) ? -1e30f : s;
          }
        // ---- row max via DPP ----
        float pm[4];
#pragma unroll
        for (int rr = 0; rr < 4; ++rr) pm[rr] = fmaxf(sv[0][rr], sv[1][rr]);
#pragma unroll
        for (int rr = 0; rr < 4; ++rr) {
          pm[rr] = fmaxf(pm[rr], DPPF(pm[rr], 0xB1));
          pm[rr] = fmaxf(pm[rr], DPPF(pm[rr], 0x4E));
          pm[rr] = fmaxf(pm[rr], DPPF(pm[rr], 0x141));
          pm[rr] = fmaxf(pm[rr], DPPF(pm[rr], 0x140));
        }
        // ---- defer-rescale (T13) ----
        bool ok = true;
#pragma unroll
        for (int rr = 0; rr < 4; ++rr) ok = ok && (pm[rr] <= mrow[rr] + 8.f);
        if (!__all((int)ok)) {
#pragma unroll
          for (int rr = 0; rr < 4; ++rr) {
            const float mnew = fmaxf(mrow[rr], pm[rr]);
            const float corr = __expf(mrow[rr] - mnew);
            mrow[rr] = mnew;
            lrow[rr] *= corr;
#pragma unroll
            for (int ht = 0; ht < 8; ++ht) oacc[ht][rr] *= corr;
          }
        }
        // ---- P = exp(S - m), wave-private LDS tile, row-sum via DPP ----
        float rs[4];
#pragma unroll
        for (int rr = 0; rr < 4; ++rr) {
          const float p0 = __expf(sv[0][rr] - mrow[rr]);
          const float p1 = __expf(sv[1][rr] - mrow[rr]);
          Pl[wave][g * 4 + rr][lr] = __float2bfloat16(p0);
          Pl[wave][g * 4 + rr][16 + lr] = __float2bfloat16(p1);
          rs[rr] = p0 + p1;
        }
#pragma unroll
        for (int rr = 0; rr < 4; ++rr) {
          rs[rr] += DPPF(rs[rr], 0xB1);
          rs[rr] += DPPF(rs[rr], 0x4E);
          rs[rr] += DPPF(rs[rr], 0x141);
          rs[rr] += DPPF(rs[rr], 0x140);
        }
#pragma unroll
        for (int rr = 0; rr < 4; ++rr) lrow[rr] += rs[rr];
        // ---- PV ----
        bf16x8 pf = *reinterpret_cast<const bf16x8*>(&Pl[wave][lr][g * 8]);
#pragma unroll
        for (int ht = 0; ht < 8; ++ht)
          oacc[ht] = __builtin_amdgcn_mfma_f32_16x16x32_bf16(pf, vf[ht],
                                                             oacc[ht], 0, 0, 0);
      }
      __hip_bfloat16* t = bufA; bufA = bufB; bufB = t;
    }

    // ---- kp-pair merge ----
    __syncthreads();   // all waves past last compute before Obuf publish
    if (kp == 1) {
#pragma unroll
      for (int ht = 0; ht < 8; ++ht)
#pragma unroll
        for (int rr = 0; rr < 4; ++rr)
          Obuf[qt][g * 4 + rr][ht * 16 + lr] = oacc[ht][rr];
      if (lr == 0) {
#pragma unroll
        for (int rr = 0; rr < 4; ++rr) {
          mbuf[wave][g * 4 + rr] = mrow[rr];
          lbuf[wave][g * 4 + rr] = lrow[rr];
        }
      }
    }
    __syncthreads();
    if (kp == 0) {
#pragma unroll
      for (int rr = 0; rr < 4; ++rr) {
        const float mB = mbuf[wave + 1][g * 4 + rr];
        const float lB = lbuf[wave + 1][g * 4 + rr];
        const float M = fmaxf(mrow[rr], mB);
        const float a = __expf(mrow[rr] - M);
        const float bt = __expf(mB - M);
        lrow[rr] = a * lrow[rr] + bt * lB;
        mrow[rr] = M;
#pragma unroll
        for (int ht = 0; ht < 8; ++ht)
          oacc[ht][rr] =
              a * oacc[ht][rr] + bt * Obuf[qt][g * 4 + rr][ht * 16 + lr];
      }
      if (mode == 0) {
#pragma unroll
        for (int ht = 0; ht < 8; ++ht)
#pragma unroll
          for (int rr = 0; rr < 4; ++rr) {
            const int qr = qrow0 + g * 4 + rr;
            out[((size_t)b * T_SEQ + qr) * H_DIM + ht * 16 + lr] =
                oacc[ht][rr] / lrow[rr];
          }
      } else {
        float* PO = (mode == 1) ? PA_O : PB_O;
        float* Pm = (mode == 1) ? PA_ml : PB_ml;
        const int slot = tile - 16;
#pragma unroll
        for (int rr = 0; rr < 4; ++rr) {
          const size_t pr = (size_t)(b * 16 + slot) * 64 + qt * 16 + g * 4 + rr;
#pragma unroll
          for (int ht = 0; ht < 8; ++ht)
            PO[pr * 128 + ht * 16 + lr] = oacc[ht][rr];
          if (lr == 0) {
            Pm[pr * 2 + 0] = mrow[rr];
            Pm[pr * 2 + 1] = lrow[rr];
          }
        }
      }
    }
    __syncthreads();
  };

  if (u < 16) {
    process(u, 0, u, 0);                 // light tile, full, direct out
    process(31 - u, 0, 15 - u, 1);       // heavy tile, early keys, partial A
  } else {
    const int v = u - 16;
    process(31 - v, 16 - v, 31 - v, 2);  // heavy tile, late keys, partial B
  }
}

// Merge the two partials of each heavy tile. grid = 8*16 = 128 blocks.
__global__ __launch_bounds__(256) void combine_kernel(
    const float* __restrict__ PA_O, const float* __restrict__ PA_ml,
    const float* __restrict__ PB_O, const float* __restrict__ PB_ml,
    float* __restrict__ out) {
  const int b = blockIdx.x >> 4;
  const int s = blockIdx.x & 15;
  const int tid = threadIdx.x;
  const int row = tid >> 2;          // 0..63
  const int c0 = (tid & 3) * 32;
  const size_t pr = (size_t)(b * 16 + s) * 64 + row;
  const float mA = PA_ml[pr * 2], lA = PA_ml[pr * 2 + 1];
  const float mB = PB_ml[pr * 2], lB = PB_ml[pr * 2 + 1];
  const float M = fmaxf(mA, mB);
  const float a = __expf(mA - M), bb = __expf(mB - M);
  const float inv = 1.f / (a * lA + bb * lB);
  const float* oa = PA_O + pr * 128 + c0;
  const float* ob = PB_O + pr * 128 + c0;
  float* op = out + ((size_t)b * T_SEQ + (16 + s) * 64 + row) * H_DIM + c0;
#pragma unroll
  for (int i = 0; i < 32; i += 4) {
    const float4 x = *reinterpret_cast<const float4*>(oa + i);
    const float4 y = *reinterpret_cast<const float4*>(ob + i);
    float4 z;
    z.x = (a * x.x + bb * y.x) * inv;
    z.y = (a * x.y + bb * y.y) * inv;
    z.z = (a * x.z + bb * y.z) * inv;
    z.w = (a * x.w + bb * y.w) * inv;
    *reinterpret_cast<float4*>(op + i) = z;
  }
}

extern "C" void kernel_launch(void* const* d_in, const int* in_sizes, int n_in,
                              void* d_out, int out_size, void* d_ws, size_t ws_size,
                              hipStream_t stream) {
  const float* x = (const float*)d_in[0];
  const float* Wq = (const float*)d_in[1];
  const float* Wk = (const float*)d_in[2];
  const float* Wv = (const float*)d_in[3];
  float* out = (float*)d_out;

  __hip_bfloat16* Wt = (__hip_bfloat16*)d_ws;
  __hip_bfloat16* qbuf = Wt + (size_t)3 * 128 * 1024;
  __hip_bfloat16* kbuf = qbuf + (size_t)NTOK * H_DIM;
  __hip_bfloat16* vbuf = kbuf + (size_t)NTOK * H_DIM;
  float* fbase = (float*)(vbuf + (size_t)NBATCH * H_DIM * T_SEQ);
  float* PA_O = fbase;                       // 8*16*64*128 = 1,048,576 f
  float* PA_ml = PA_O + (size_t)1048576;     // 16,384 f
  float* PB_O = PA_ml + 16384;
  float* PB_ml = PB_O + (size_t)1048576;

  hipLaunchKernelGGL(prep_w_kernel, dim3(384), dim3(256), 0, stream, Wq, Wk, Wv, Wt);
  hipLaunchKernelGGL(proj_kernel, dim3(256), dim3(512), 0, stream, x, Wt, qbuf,
                     kbuf, vbuf);
  hipLaunchKernelGGL(attn_kernel, dim3(256), dim3(512), 0, stream, qbuf, kbuf,
                     vbuf, out, PA_O, PA_ml, PB_O, PB_ml);
  hipLaunchKernelGGL(combine_kernel, dim3(128), dim3(256), 0, stream, PA_O,
                     PA_ml, PB_O, PB_ml, out);
}